// Round 15
// baseline (1202.231 us; speedup 1.0000x reference)
//
#include <hip/hip_runtime.h>
#include <hip/hip_bf16.h>

typedef unsigned short u16;
typedef unsigned int u32;

static const int DD = 768;
static const int SS = 2048;
static const int BB = 8;
static const int HH = 12;
static const int NBLK = 16;   // S / 128
static const int ROWS = BB * SS;          // 16384
static const size_t AD = (size_t)ROWS * DD;   // activation element count
static const size_t D2 = (size_t)DD * DD;
static const size_t DI = (size_t)DD * 3072;

typedef __attribute__((ext_vector_type(8))) short short8;
typedef __attribute__((ext_vector_type(4))) float f32x4;

union U16x8 { uint4 u; short8 s; };

__device__ __forceinline__ float bl(u32 u) { return __uint_as_float(u << 16); }
__device__ __forceinline__ float bh(u32 u) { return __uint_as_float(u & 0xffff0000u); }
__device__ __forceinline__ u16 f2b(float f) {
    u32 u = __float_as_uint(f);
    u += 0x7fffu + ((u >> 16) & 1u);
    return (u16)(u >> 16);
}
__device__ __forceinline__ u32 pack2(float lo, float hi) {
    return (u32)f2b(lo) | ((u32)f2b(hi) << 16);
}

// async global->LDS, 16B per lane (dest is wave-uniform base + lane*16)
__device__ __forceinline__ void gload16(const u16* g, u16* l) {
    __builtin_amdgcn_global_load_lds(
        (const __attribute__((address_space(1))) void*)g,
        (__attribute__((address_space(3))) void*)l, 16, 0, 0);
}

// fast GELU (tanh form): v * sigmoid(2z), z = 0.7978845608(v + 0.044715 v^3)
__device__ __forceinline__ float gelu_fast(float v) {
    float z2 = 1.5957691216f * (v + 0.044715f * v * v * v);
    z2 = fminf(z2, 80.f);
    float e = __expf(z2);
    return v * (e / (e + 1.0f));
}

// ---------------- elementwise f32 -> bf16 cast ----------------
__global__ __launch_bounds__(256) void cast_bf16(const float* __restrict__ x,
                                                 u16* __restrict__ xb, int n) {
    int i = (blockIdx.x * 256 + threadIdx.x) * 4;
    if (i < n) {
        float4 v = *reinterpret_cast<const float4*>(x + i);
        uint2 p;
        p.x = pack2(v.x, v.y);
        p.y = pack2(v.z, v.w);
        *reinterpret_cast<uint2*>(xb + i) = p;
    }
}

// ---------------- cast + transpose: W[K,N] f32 -> WT[N,K] bf16 ----------------
__global__ __launch_bounds__(256) void cast_transpose(const float* __restrict__ W,
                                                      u16* __restrict__ WT,
                                                      int K, int N) {
    __shared__ float tile[32][33];
    int bx = blockIdx.x;  // along N
    int by = blockIdx.y;  // along K
    int tx = threadIdx.x; // 0..31
    int ty = threadIdx.y; // 0..7
#pragma unroll
    for (int i = 0; i < 4; i++) {
        int kr = by * 32 + ty + i * 8;
        tile[ty + i * 8][tx] = W[(size_t)kr * N + bx * 32 + tx];
    }
    __syncthreads();
#pragma unroll
    for (int i = 0; i < 4; i++) {
        int nr = bx * 32 + ty + i * 8;
        WT[(size_t)nr * K + by * 32 + tx] = f2b(tile[tx][ty + i * 8]);
    }
}

// ------- 128x128 MFMA GEMM: A via LDS dbuf, B DIRECT from global (L2) -------
// C[M,N] = A[M,K](bf16) @ BT[N,K](bf16)^T + bias
// r14 audit: LDS traffic (16KB gload-write + 32KB ds_read per block K-step)
// is the wall (~490cy vs 78cy MFMA -> 23% MfmaUtil). B is the weight matrix
// (per-tn panel 196KB, L2-hot across the tm sweep), so B fragments are read
// straight to registers — the direct-global address equals the LDS-logical
// layout (no swizzle needed on B). LDS traffic/block-K-step: 48KB -> 24KB.
// B for step t+1 is loaded into a named register double-buffer BEFORE the
// barrier (syncthreads drains vmcnt(0) -> completes into regs during the
// MFMA tail; rule #20: static names, no runtime-indexed arrays).
// A-side swizzle unchanged (rule #21, both sides): phys slot = log ^ ((row>>1)&3).
// EPI 0: bf16 out; 2: gelu->bf16 out; 5: QKV row-major (band uniform/block)
// NT = K/32 even at all call sites (24, 96). LDS 2 x 8KB = 16KB.
template <int EPI>
__global__ __launch_bounds__(256, 3) void gemm128(const u16* __restrict__ A,
                                                  const u16* __restrict__ BT,
                                                  const float* __restrict__ b0,
                                                  const float* __restrict__ b1,
                                                  const float* __restrict__ b2,
                                                  void* __restrict__ C0,
                                                  void* __restrict__ C1,
                                                  void* __restrict__ C2,
                                                  int M, int N, int K, int NTN) {
    extern __shared__ u16 smem[];  // 2 slots x 4096 u16 (8KB) = 16KB (A only)
    const int tid = threadIdx.x;
    const int nwg = gridDim.x;
    int wg = blockIdx.x;
    // chunked bijective XCD swizzle (all grids divisible by 8)
    wg = (wg & 7) * (nwg >> 3) + (wg >> 3);
    const int tn = wg % NTN, tm = wg / NTN;   // row-major: A M-panel stays hot
    const int m0 = tm * 128, n0 = tn * 128;
    const int lane = tid & 63, w = tid >> 6;
    const int wr = w >> 1, wc = w & 1;
    const int lr = lane & 15, ls = lane >> 4;
    const int sl = ls ^ ((lr >> 1) & 3);      // swizzled A read slot

    const int r3 = tid >> 2, c2 = tid & 3;
    const int kswz = ((c2 ^ ((r3 >> 1) & 3)) << 3);  // pre-swizzled src k-offset
    const u16* sA = A + (size_t)(m0 + r3) * K + kswz;   // incremental A source
    const size_t rstep = (size_t)64 * K;       // 64 rows per staging chunk

    // direct-global B fragment base: row (n0 + wc*64 + lr), k-chunk ls*8
    const u16* bRow = BT + (size_t)(n0 + wc * 64 + lr) * K + ls * 8;
    const size_t bStride = (size_t)16 * K;     // ni -> +16 rows

    f32x4 acc[4][4];
#pragma unroll
    for (int i = 0; i < 4; i++)
#pragma unroll
        for (int j = 0; j < 4; j++) acc[i][j] = (f32x4){0.f, 0.f, 0.f, 0.f};

    U16x8 bfA[4], bfB[4];

#define STAGE_SLOT(SLOT)                                                      \
    {                                                                         \
        u16* pA = smem + (SLOT) * 4096 + tid * 8;                             \
        gload16(sA, pA);                                                      \
        gload16(sA + rstep, pA + 2048);                                       \
        sA += 32;                                                             \
    }
#define LOAD_B(DST, KT)                                                       \
    {                                                                         \
        const u16* _bp = bRow + (size_t)(KT) * 32;                            \
        DST[0].u = *(const uint4*)(_bp);                                      \
        DST[1].u = *(const uint4*)(_bp + bStride);                            \
        DST[2].u = *(const uint4*)(_bp + 2 * bStride);                        \
        DST[3].u = *(const uint4*)(_bp + 3 * bStride);                        \
    }
#define COMPUTE_SLOT(SLOT, BF)                                                \
    {                                                                         \
        const u16* bufA = smem + (SLOT) * 4096 + (wr * 64 + lr) * 32;         \
        U16x8 af[4];                                                          \
        _Pragma("unroll") for (int mi = 0; mi < 4; mi++)                      \
            af[mi].u = *(const uint4*)(bufA + mi * 512 + sl * 8);             \
        _Pragma("unroll") for (int mi = 0; mi < 4; mi++)                      \
            _Pragma("unroll") for (int ni = 0; ni < 4; ni++)                  \
                acc[mi][ni] = __builtin_amdgcn_mfma_f32_16x16x32_bf16(        \
                    af[mi].s, BF[ni].s, acc[mi][ni], 0, 0, 0);                \
    }

    const int NT = K >> 5;   // even at all call sites
    STAGE_SLOT(0)            // prologue: A tile 0 -> slot 0
    LOAD_B(bfA, 0)           // B tile 0 -> regs
    __syncthreads();

    for (int t = 0; t < NT; t += 2) {
        const int k1 = (t + 1 < NT) ? t + 1 : NT - 1;   // clamped (redundant ok)
        const int k2 = (t + 2 < NT) ? t + 2 : NT - 1;
        if (t + 1 < NT) STAGE_SLOT(1)   // A tile t+1
        LOAD_B(bfB, k1)                 // B tile t+1 -> regs (completes at barrier)
        COMPUTE_SLOT(0, bfA)            // compute tile t
        __syncthreads();
        if (t + 2 < NT) STAGE_SLOT(0)   // A tile t+2
        LOAD_B(bfA, k2)                 // B tile t+2 -> regs
        COMPUTE_SLOT(1, bfB)            // compute tile t+1
        __syncthreads();
    }
#undef STAGE_SLOT
#undef LOAD_B
#undef COMPUTE_SLOT

    // epilogue
    u16* dstQ = (u16*)C0;
    const float* bp = b0;
    int cbase = 0;
    if (EPI == 5) {                    // band uniform per block (768 % 128 == 0)
        int band = n0 / 768;
        dstQ = (band == 0) ? (u16*)C0 : (band == 1) ? (u16*)C1 : (u16*)C2;
        bp = (band == 0) ? b0 : (band == 1) ? b1 : b2;
        cbase = n0 - band * 768;
    }
#pragma unroll
    for (int mi = 0; mi < 4; mi++) {
        int row0 = m0 + wr * 64 + mi * 16 + ls * 4;
#pragma unroll
        for (int ni = 0; ni < 4; ni++) {
            int cloc = wc * 64 + ni * 16 + lr;
            float v[4];
            if (EPI == 5) {
                float bs = bp[cbase + cloc];
#pragma unroll
                for (int r = 0; r < 4; r++) {
                    v[r] = acc[mi][ni][r] + bs;
                    dstQ[(size_t)(row0 + r) * 768 + cbase + cloc] = f2b(v[r]);
                }
            } else {
                int col = n0 + cloc;
                float bs = b0[col];
#pragma unroll
                for (int r = 0; r < 4; r++) {
                    v[r] = acc[mi][ni][r] + bs;
                    if (EPI == 2) v[r] = gelu_fast(v[r]);
                    ((u16*)C0)[(size_t)(row0 + r) * N + col] = f2b(v[r]);
                }
            }
        }
    }
}

// ------- residual add + LayerNorm, wave-per-row (no LDS, no barriers) -------
// a: bf16 [rows][768]; res: f32 or bf16; writes bf16 ob and optionally f32 of.
// 4 rows per 256-thread block; lane handles 12 elems (3 x 4 at stride 256).
template <bool RESF32, bool OUTF32>
__global__ __launch_bounds__(256) void resid_ln2(const u16* __restrict__ a,
                                                 const void* __restrict__ res,
                                                 const float* __restrict__ g,
                                                 const float* __restrict__ be,
                                                 float* __restrict__ of,
                                                 u16* __restrict__ ob) {
    const int row = blockIdx.x * 4 + (threadIdx.x >> 6);
    const int lane = threadIdx.x & 63;
    const size_t base = (size_t)row * 768;
    float v[12];
    float s = 0.f;
#pragma unroll
    for (int i = 0; i < 3; i++) {
        int c = lane * 4 + i * 256;
        uint2 av = *reinterpret_cast<const uint2*>(a + base + c);
        float rv0, rv1, rv2, rv3;
        if (RESF32) {
            float4 r4 = *reinterpret_cast<const float4*>((const float*)res + base + c);
            rv0 = r4.x; rv1 = r4.y; rv2 = r4.z; rv3 = r4.w;
        } else {
            uint2 r2 = *reinterpret_cast<const uint2*>((const u16*)res + base + c);
            rv0 = bl(r2.x); rv1 = bh(r2.x); rv2 = bl(r2.y); rv3 = bh(r2.y);
        }
        v[i * 4 + 0] = bl(av.x) + rv0;
        v[i * 4 + 1] = bh(av.x) + rv1;
        v[i * 4 + 2] = bl(av.y) + rv2;
        v[i * 4 + 3] = bh(av.y) + rv3;
        s += v[i * 4 + 0] + v[i * 4 + 1] + v[i * 4 + 2] + v[i * 4 + 3];
    }
#pragma unroll
    for (int o = 1; o < 64; o <<= 1) s += __shfl_xor(s, o);
    float mean = s * (1.f / 768.f);
    float q = 0.f;
#pragma unroll
    for (int i = 0; i < 12; i++) {
        float d = v[i] - mean;
        q += d * d;
    }
#pragma unroll
    for (int o = 1; o < 64; o <<= 1) q += __shfl_xor(q, o);
    float inv = rsqrtf(q * (1.f / 768.f) + 1e-12f);
#pragma unroll
    for (int i = 0; i < 3; i++) {
        int c = lane * 4 + i * 256;
        float4 g4 = *reinterpret_cast<const float4*>(g + c);
        float4 b4 = *reinterpret_cast<const float4*>(be + c);
        float y0 = (v[i * 4 + 0] - mean) * inv * g4.x + b4.x;
        float y1 = (v[i * 4 + 1] - mean) * inv * g4.y + b4.y;
        float y2 = (v[i * 4 + 2] - mean) * inv * g4.z + b4.z;
        float y3 = (v[i * 4 + 3] - mean) * inv * g4.w + b4.w;
        if (OUTF32) {
            float4 o4 = {y0, y1, y2, y3};
            *reinterpret_cast<float4*>(of + base + c) = o4;
        }
        uint2 ob2;
        ob2.x = pack2(y0, y1);
        ob2.y = pack2(y2, y3);
        *reinterpret_cast<uint2*>(ob + base + c) = ob2;
    }
}

// ---------------- halo block attention (MFMA) ----------------
// Q, K, V all row-major [B*S][768] bf16. V transposed into LDS at stage time.
__global__ __launch_bounds__(256) void attn_mfma(const u16* __restrict__ Q,
                                                 const u16* __restrict__ Kx,
                                                 const u16* __restrict__ Vx,
                                                 u16* __restrict__ Ctx) {
    __shared__ u16 sm0[128 * 104];  // P (padded stride 104); also K [192][64] swizzled
    __shared__ u16 sm1[64 * 192];   // V^T [64 feat][192 tok] chunk-swizzled
    u16* Ks = sm0;
    u16* Ps = sm0;
    u16* Vs = sm1;

    const int bid = blockIdx.x;
    const int h = bid % HH;
    const int n = (bid / HH) % NBLK;
    const int b = bid / (HH * NBLK);
    const int tid = threadIdx.x;
    const int lane = tid & 63, w = tid >> 6;
    const int lr = lane & 15, ls = lane >> 4;
    const int s0 = n * 128 - 32;

#pragma unroll
    for (int j = 0; j < 6; j++) {
        int r = (tid >> 3) + j * 32;
        int c = tid & 7;
        int s = min(max(s0 + r, 0), SS - 1);
        uint4 kv = *reinterpret_cast<const uint4*>(Kx + ((size_t)(b * SS + s)) * 768 + h * 64 + c * 8);
        int byteo = r * 128 + ((c * 16) ^ ((r & 7) << 4));
        *reinterpret_cast<uint4*>(Ks + (byteo >> 1)) = kv;
    }
#pragma unroll
    for (int j = 0; j < 6; j++) {
        int r = (tid >> 3) + j * 32;          // window token
        int c = tid & 7;                      // feature chunk (8 features)
        int s = min(max(s0 + r, 0), SS - 1);
        uint4 vv = *reinterpret_cast<const uint4*>(Vx + ((size_t)(b * SS + s)) * 768 + h * 64 + c * 8);
        const u16* e = reinterpret_cast<const u16*>(&vv);
        int chunk = r >> 3;
        int bo = (r & 7) * 2;
#pragma unroll
        for (int i = 0; i < 8; i++) {
            int d = c * 8 + i;
            int pch = chunk ^ (d & 7) ^ ((d >> 3) & 7);
            Vs[(d * 384 + pch * 16 + bo) >> 1] = e[i];
        }
    }
    __syncthreads();

    const int qrow0 = b * SS + n * 128 + w * 32;
    U16x8 qf[2][2];
#pragma unroll
    for (int mi = 0; mi < 2; mi++)
#pragma unroll
        for (int ks = 0; ks < 2; ks++)
            qf[mi][ks].u = *reinterpret_cast<const uint4*>(
                Q + (size_t)(qrow0 + mi * 16 + lr) * 768 + h * 64 + ks * 32 + ls * 8);

    f32x4 sc[2][12];
#pragma unroll
    for (int mi = 0; mi < 2; mi++)
#pragma unroll
        for (int jt = 0; jt < 12; jt++) sc[mi][jt] = (f32x4){0.f, 0.f, 0.f, 0.f};
#pragma unroll
    for (int jt = 0; jt < 12; jt++) {
        U16x8 kf[2];
#pragma unroll
        for (int ks = 0; ks < 2; ks++) {
            int r = jt * 16 + lr;
            int byteo = r * 128 + ((ks * 64 + ls * 16) ^ ((r & 7) << 4));
            kf[ks].u = *reinterpret_cast<const uint4*>(Ks + (byteo >> 1));
        }
#pragma unroll
        for (int mi = 0; mi < 2; mi++)
#pragma unroll
            for (int ks = 0; ks < 2; ks++)
                sc[mi][jt] = __builtin_amdgcn_mfma_f32_16x16x32_bf16(
                    qf[mi][ks].s, kf[ks].s, sc[mi][jt], 0, 0, 0);
    }

    const int lo = (n == 0) ? 32 : 0;
    const int hi = (n == NBLK - 1) ? 160 : 192;
    float mx[2][4], sm[2][4], inv[2][4];
#pragma unroll
    for (int mi = 0; mi < 2; mi++)
#pragma unroll
        for (int r = 0; r < 4; r++) { mx[mi][r] = -3.0e38f; sm[mi][r] = 0.f; }
#pragma unroll
    for (int jt = 0; jt < 12; jt++) {
        int col = jt * 16 + lr;
        bool valid = (col >= lo) && (col < hi);
#pragma unroll
        for (int mi = 0; mi < 2; mi++)
#pragma unroll
            for (int r = 0; r < 4; r++) {
                float v = valid ? sc[mi][jt][r] * 0.125f : -3.0e38f;
                sc[mi][jt][r] = v;
                mx[mi][r] = fmaxf(mx[mi][r], v);
            }
    }
#pragma unroll
    for (int o = 1; o <= 8; o <<= 1)
#pragma unroll
        for (int mi = 0; mi < 2; mi++)
#pragma unroll
            for (int r = 0; r < 4; r++)
                mx[mi][r] = fmaxf(mx[mi][r], __shfl_xor(mx[mi][r], o));
#pragma unroll
    for (int jt = 0; jt < 12; jt++)
#pragma unroll
        for (int mi = 0; mi < 2; mi++)
#pragma unroll
            for (int r = 0; r < 4; r++) {
                float p = __expf(sc[mi][jt][r] - mx[mi][r]);
                sc[mi][jt][r] = p;
                sm[mi][r] += p;
            }
#pragma unroll
    for (int o = 1; o <= 8; o <<= 1)
#pragma unroll
        for (int mi = 0; mi < 2; mi++)
#pragma unroll
            for (int r = 0; r < 4; r++)
                sm[mi][r] += __shfl_xor(sm[mi][r], o);
#pragma unroll
    for (int mi = 0; mi < 2; mi++)
#pragma unroll
        for (int r = 0; r < 4; r++) inv[mi][r] = 1.0f / sm[mi][r];

    f32x4 oacc[2][4];
#pragma unroll
    for (int mi = 0; mi < 2; mi++)
#pragma unroll
        for (int dt = 0; dt < 4; dt++) oacc[mi][dt] = (f32x4){0.f, 0.f, 0.f, 0.f};
    __syncthreads();

#pragma unroll
    for (int ph = 0; ph < 2; ph++) {
#pragma unroll
        for (int jj = 0; jj < 6; jj++) {
            int jt = ph * 6 + jj;
#pragma unroll
            for (int mi = 0; mi < 2; mi++) {
                int row = w * 32 + mi * 16 + ls * 4;
#pragma unroll
                for (int r = 0; r < 4; r++)
                    Ps[(row + r) * 104 + jj * 16 + lr] = f2b(sc[mi][jt][r]);
            }
        }
        __syncthreads();
#pragma unroll
        for (int kk = 0; kk < 3; kk++) {
            U16x8 pf[2], vf[4];
#pragma unroll
            for (int mi = 0; mi < 2; mi++)
                pf[mi].u = *reinterpret_cast<const uint4*>(
                    Ps + (w * 32 + mi * 16 + lr) * 104 + kk * 32 + ls * 8);
#pragma unroll
            for (int dt = 0; dt < 4; dt++) {
                int rrow = dt * 16 + lr;
                int lch = ph * 12 + kk * 4 + ls;
                int pch = lch ^ (rrow & 7) ^ ((rrow >> 3) & 7);
                vf[dt].u = *reinterpret_cast<const uint4*>(Vs + ((rrow * 384 + pch * 16) >> 1));
            }
#pragma unroll
            for (int mi = 0; mi < 2; mi++)
#pragma unroll
                for (int dt = 0; dt < 4; dt++)
                    oacc[mi][dt] = __builtin_amdgcn_mfma_f32_16x16x32_bf16(
                        pf[mi].s, vf[dt].s, oacc[mi][dt], 0, 0, 0);
        }
        __syncthreads();
    }

#pragma unroll
    for (int mi = 0; mi < 2; mi++)
#pragma unroll
        for (int dt = 0; dt < 4; dt++)
#pragma unroll
            for (int r = 0; r < 4; r++) {
                float v = oacc[mi][dt][r] * inv[mi][r];
                Ctx[(size_t)(qrow0 + mi * 16 + ls * 4 + r) * 768 + h * 64 + dt * 16 + lr] = f2b(v);
            }
}

extern "C" void kernel_launch(void* const* d_in, const int* in_sizes, int n_in,
                              void* d_out, int out_size, void* d_ws, size_t ws_size,
                              hipStream_t stream) {
    (void)in_sizes; (void)n_in; (void)out_size; (void)ws_size;
    const float* x    = (const float*)d_in[0];
    const float* Wq   = (const float*)d_in[1];
    const float* bq   = (const float*)d_in[2];
    const float* Wk   = (const float*)d_in[3];
    const float* bk   = (const float*)d_in[4];
    const float* Wv   = (const float*)d_in[5];
    const float* bv   = (const float*)d_in[6];
    const float* Wo   = (const float*)d_in[7];
    const float* bo   = (const float*)d_in[8];
    const float* ln1g = (const float*)d_in[9];
    const float* ln1b = (const float*)d_in[10];
    const float* W1   = (const float*)d_in[11];
    const float* b1   = (const float*)d_in[12];
    const float* W2   = (const float*)d_in[13];
    const float* b2   = (const float*)d_in[14];
    const float* ln2g = (const float*)d_in[15];
    const float* ln2b = (const float*)d_in[16];
    float* out = (float*)d_out;

    char* ws = (char*)d_ws;
    size_t off = 0;
    auto alloc = [&](size_t bytes) -> char* {
        char* p = ws + off;
        off += (bytes + 255) & ~(size_t)255;
        return p;
    };
    u16* WqkvT = (u16*)alloc(2 * 3 * D2 * sizeof(u16));  // per layer: [Q;K;V] rows
    u16* WoT   = (u16*)alloc(2 * D2 * sizeof(u16));
    u16* W1T   = (u16*)alloc(2 * DI * sizeof(u16));
    u16* W2T   = (u16*)alloc(2 * DI * sizeof(u16));
    u16* Xb    = (u16*)alloc(AD * sizeof(u16));
    u16* RegA  = (u16*)alloc(4 * AD * sizeof(u16)); // Qb,Kb,Vb,Ctxb; reused as H1b
    u16*   AttnB = (u16*)alloc(AD * sizeof(u16));
    u16*   H2b   = (u16*)alloc(AD * sizeof(u16));
    u16* Qb = RegA;
    u16* Kb = RegA + AD;
    u16* Vb = RegA + 2 * AD;    // row-major like Q/K
    u16* Ctxb = RegA + 3 * AD;
    u16* H1b = RegA;

    {
        int nelem = ROWS * DD;
        cast_bf16<<<dim3(nelem / 4 / 256), dim3(256), 0, stream>>>(x, Xb, nelem);
    }
    for (int l = 0; l < 2; l++) {
        u16* base = WqkvT + (size_t)l * 3 * D2;
        cast_transpose<<<dim3(24, 24), dim3(32, 8), 0, stream>>>(Wq + l * D2, base, 768, 768);
        cast_transpose<<<dim3(24, 24), dim3(32, 8), 0, stream>>>(Wk + l * D2, base + D2, 768, 768);
        cast_transpose<<<dim3(24, 24), dim3(32, 8), 0, stream>>>(Wv + l * D2, base + 2 * D2, 768, 768);
        cast_transpose<<<dim3(24, 24), dim3(32, 8), 0, stream>>>(Wo + l * D2, WoT + l * D2, 768, 768);
        cast_transpose<<<dim3(96, 24), dim3(32, 8), 0, stream>>>(W1 + l * DI, W1T + l * DI, 768, 3072);
        cast_transpose<<<dim3(24, 96), dim3(32, 8), 0, stream>>>(W2 + l * DI, W2T + l * DI, 3072, 768);
    }

    const size_t LDSB = 16384;   // 2 slots x 8KB (A only)
    const float* xres = x;
    for (int l = 0; l < 2; l++) {
        // fused QKV: N=2304 (bands Q|K|V), all outputs row-major bf16
        gemm128<5><<<dim3(128 * 18), 256, LDSB, stream>>>(
            Xb, WqkvT + (size_t)l * 3 * D2, bq + l * 768, bk + l * 768, bv + l * 768,
            Qb, Kb, Vb, ROWS, 2304, 768, 18);
        attn_mfma<<<dim3(BB * NBLK * HH), 256, 0, stream>>>(Qb, Kb, Vb, Ctxb);
        gemm128<0><<<dim3(128 * 6), 256, LDSB, stream>>>(
            Ctxb, WoT + l * D2, bo + l * 768, nullptr, nullptr,
            H2b, nullptr, nullptr, ROWS, 768, 768, 6);
        // LN1: bf16 GEMM out + f32 residual -> bf16 attn_out (no f32 copy)
        resid_ln2<true, false><<<dim3(ROWS / 4), 256, 0, stream>>>(
            H2b, (const void*)xres, ln1g + l * 768, ln1b + l * 768, nullptr, AttnB);
        gemm128<2><<<dim3(128 * 24), 256, LDSB, stream>>>(
            AttnB, W1T + l * DI, b1 + l * 3072, nullptr, nullptr,
            H1b, nullptr, nullptr, ROWS, 3072, 768, 24);
        gemm128<0><<<dim3(128 * 6), 256, LDSB, stream>>>(
            H1b, W2T + l * DI, b2 + l * 768, nullptr, nullptr,
            H2b, nullptr, nullptr, ROWS, 768, 3072, 6);
        float* outl = out + (size_t)l * AD;
        // LN2: bf16 GEMM out + bf16 attn_out residual -> f32 layer out + bf16 next-X
        resid_ln2<false, true><<<dim3(ROWS / 4), 256, 0, stream>>>(
            H2b, (const void*)AttnB, ln2g + l * 768, ln2b + l * 768, outl, Xb);
        xres = outl;
    }
}

// Round 16
// 867.027 us; speedup vs baseline: 1.3866x; 1.3866x over previous
//
#include <hip/hip_runtime.h>
#include <hip/hip_bf16.h>

typedef unsigned short u16;
typedef unsigned int u32;

static const int DD = 768;
static const int SS = 2048;
static const int BB = 8;
static const int HH = 12;
static const int NBLK = 16;   // S / 128
static const int ROWS = BB * SS;          // 16384
static const size_t AD = (size_t)ROWS * DD;   // activation element count
static const size_t D2 = (size_t)DD * DD;
static const size_t DI = (size_t)DD * 3072;

typedef __attribute__((ext_vector_type(8))) short short8;
typedef __attribute__((ext_vector_type(4))) float f32x4;

union U16x8 { uint4 u; short8 s; };

__device__ __forceinline__ float bl(u32 u) { return __uint_as_float(u << 16); }
__device__ __forceinline__ float bh(u32 u) { return __uint_as_float(u & 0xffff0000u); }
__device__ __forceinline__ u16 f2b(float f) {
    u32 u = __float_as_uint(f);
    u += 0x7fffu + ((u >> 16) & 1u);
    return (u16)(u >> 16);
}
__device__ __forceinline__ u32 pack2(float lo, float hi) {
    return (u32)f2b(lo) | ((u32)f2b(hi) << 16);
}

// async global->LDS, 16B per lane (dest is wave-uniform base + lane*16)
__device__ __forceinline__ void gload16(const u16* g, u16* l) {
    __builtin_amdgcn_global_load_lds(
        (const __attribute__((address_space(1))) void*)g,
        (__attribute__((address_space(3))) void*)l, 16, 0, 0);
}

// fast GELU (tanh form): v * sigmoid(2z), z = 0.7978845608(v + 0.044715 v^3)
__device__ __forceinline__ float gelu_fast(float v) {
    float z2 = 1.5957691216f * (v + 0.044715f * v * v * v);
    z2 = fminf(z2, 80.f);
    float e = __expf(z2);
    return v * (e / (e + 1.0f));
}

// ---------------- elementwise f32 -> bf16 cast ----------------
__global__ __launch_bounds__(256) void cast_bf16(const float* __restrict__ x,
                                                 u16* __restrict__ xb, int n) {
    int i = (blockIdx.x * 256 + threadIdx.x) * 4;
    if (i < n) {
        float4 v = *reinterpret_cast<const float4*>(x + i);
        uint2 p;
        p.x = pack2(v.x, v.y);
        p.y = pack2(v.z, v.w);
        *reinterpret_cast<uint2*>(xb + i) = p;
    }
}

// ---------------- cast + transpose: W[K,N] f32 -> WT[N,K] bf16 ----------------
__global__ __launch_bounds__(256) void cast_transpose(const float* __restrict__ W,
                                                      u16* __restrict__ WT,
                                                      int K, int N) {
    __shared__ float tile[32][33];
    int bx = blockIdx.x;  // along N
    int by = blockIdx.y;  // along K
    int tx = threadIdx.x; // 0..31
    int ty = threadIdx.y; // 0..7
#pragma unroll
    for (int i = 0; i < 4; i++) {
        int kr = by * 32 + ty + i * 8;
        tile[ty + i * 8][tx] = W[(size_t)kr * N + bx * 32 + tx];
    }
    __syncthreads();
#pragma unroll
    for (int i = 0; i < 4; i++) {
        int nr = bx * 32 + ty + i * 8;
        WT[(size_t)nr * K + by * 32 + tx] = f2b(tile[tx][ty + i * 8]);
    }
}

// ---------------- 128x128 MFMA GEMM, BK=32 dbuf, 4 blocks/CU, unroll x2 ------
// r14 structure (823us best). This round's single A/B: XCD swizzle REMOVED —
// per m160, chunked XCD swizzle costs ~2% when the working set is L3-fit
// (ours: 25-100MB, well under 256MB L3). Raster unchanged (row-major,
// consecutive wg share the A M-panel).
// EPI 0: bf16 out; 2: gelu->bf16 out; 5: QKV row-major (band uniform/block)
// Swizzle (rule #21, both sides): 16B-slot phys = logical ^ ((row>>1)&3).
// Requires NT = K/32 even (call sites: 24, 96).
template <int EPI>
__global__ __launch_bounds__(256, 4) void gemm128(const u16* __restrict__ A,
                                                  const u16* __restrict__ BT,
                                                  const float* __restrict__ b0,
                                                  const float* __restrict__ b1,
                                                  const float* __restrict__ b2,
                                                  void* __restrict__ C0,
                                                  void* __restrict__ C1,
                                                  void* __restrict__ C2,
                                                  int M, int N, int K, int NTN) {
    extern __shared__ u16 smem[];  // 2 slots x 8192 u16 (16KB) = 32KB
    const int tid = threadIdx.x;
    const int wg = blockIdx.x;     // no XCD swizzle (L3-fit working set, m160)
    const int tn = wg % NTN, tm = wg / NTN;   // row-major: A M-panel stays hot
    const int m0 = tm * 128, n0 = tn * 128;
    const int lane = tid & 63, w = tid >> 6;
    const int wr = w >> 1, wc = w & 1;
    const int lr = lane & 15, ls = lane >> 4;
    const int sl = ls ^ ((lr >> 1) & 3);      // 2-way-optimal swizzled slot

    const int r3 = tid >> 2, c2 = tid & 3;
    const int kswz = ((c2 ^ ((r3 >> 1) & 3)) << 3);  // pre-swizzled src k-offset
    const u16* sA = A + (size_t)(m0 + r3) * K + kswz;   // incremental sources
    const u16* sB = BT + (size_t)(n0 + r3) * K + kswz;
    const size_t rstep = (size_t)64 * K;       // 64 rows per chunk

    f32x4 acc[4][4];
#pragma unroll
    for (int i = 0; i < 4; i++)
#pragma unroll
        for (int j = 0; j < 4; j++) acc[i][j] = (f32x4){0.f, 0.f, 0.f, 0.f};

#define STAGE_SLOT(SLOT)                                                      \
    {                                                                         \
        u16* pA = smem + (SLOT) * 8192 + tid * 8;                             \
        u16* pB = smem + (SLOT) * 8192 + 4096 + tid * 8;                      \
        gload16(sA, pA);                                                      \
        gload16(sA + rstep, pA + 2048);                                       \
        gload16(sB, pB);                                                      \
        gload16(sB + rstep, pB + 2048);                                       \
        sA += 32;                                                             \
        sB += 32;                                                             \
    }
#define COMPUTE_SLOT(SLOT)                                                    \
    {                                                                         \
        const u16* bufA = smem + (SLOT) * 8192 + (wr * 64 + lr) * 32;         \
        const u16* bufB = smem + (SLOT) * 8192 + 4096 + (wc * 64 + lr) * 32;  \
        U16x8 af[4], bf[4];                                                   \
        _Pragma("unroll") for (int ni = 0; ni < 4; ni++)                      \
            bf[ni].u = *(const uint4*)(bufB + ni * 512 + sl * 8);             \
        _Pragma("unroll") for (int mi = 0; mi < 4; mi++)                      \
            af[mi].u = *(const uint4*)(bufA + mi * 512 + sl * 8);             \
        _Pragma("unroll") for (int mi = 0; mi < 4; mi++)                      \
            _Pragma("unroll") for (int ni = 0; ni < 4; ni++)                  \
                acc[mi][ni] = __builtin_amdgcn_mfma_f32_16x16x32_bf16(        \
                    af[mi].s, bf[ni].s, acc[mi][ni], 0, 0, 0);                \
    }

    const int NT = K >> 5;   // even at all call sites
    STAGE_SLOT(0)            // prologue: tile 0 -> slot 0
    __syncthreads();

    for (int t = 0; t < NT; t += 2) {
        if (t + 1 < NT) STAGE_SLOT(1)   // prefetch tile t+1
        COMPUTE_SLOT(0)                 // compute tile t
        __syncthreads();
        if (t + 2 < NT) STAGE_SLOT(0)   // prefetch tile t+2
        COMPUTE_SLOT(1)                 // compute tile t+1
        __syncthreads();
    }
#undef STAGE_SLOT
#undef COMPUTE_SLOT

    // epilogue
    u16* dstQ = (u16*)C0;
    const float* bp = b0;
    int cbase = 0;
    if (EPI == 5) {                    // band uniform per block (768 % 128 == 0)
        int band = n0 / 768;
        dstQ = (band == 0) ? (u16*)C0 : (band == 1) ? (u16*)C1 : (u16*)C2;
        bp = (band == 0) ? b0 : (band == 1) ? b1 : b2;
        cbase = n0 - band * 768;
    }
#pragma unroll
    for (int mi = 0; mi < 4; mi++) {
        int row0 = m0 + wr * 64 + mi * 16 + ls * 4;
#pragma unroll
        for (int ni = 0; ni < 4; ni++) {
            int cloc = wc * 64 + ni * 16 + lr;
            float v[4];
            if (EPI == 5) {
                float bs = bp[cbase + cloc];
#pragma unroll
                for (int r = 0; r < 4; r++) {
                    v[r] = acc[mi][ni][r] + bs;
                    dstQ[(size_t)(row0 + r) * 768 + cbase + cloc] = f2b(v[r]);
                }
            } else {
                int col = n0 + cloc;
                float bs = b0[col];
#pragma unroll
                for (int r = 0; r < 4; r++) {
                    v[r] = acc[mi][ni][r] + bs;
                    if (EPI == 2) v[r] = gelu_fast(v[r]);
                    ((u16*)C0)[(size_t)(row0 + r) * N + col] = f2b(v[r]);
                }
            }
        }
    }
}

// ------- residual add + LayerNorm, wave-per-row (no LDS, no barriers) -------
// a: bf16 [rows][768]; res: f32 or bf16; writes bf16 ob and optionally f32 of.
// 4 rows per 256-thread block; lane handles 12 elems (3 x 4 at stride 256).
template <bool RESF32, bool OUTF32>
__global__ __launch_bounds__(256) void resid_ln2(const u16* __restrict__ a,
                                                 const void* __restrict__ res,
                                                 const float* __restrict__ g,
                                                 const float* __restrict__ be,
                                                 float* __restrict__ of,
                                                 u16* __restrict__ ob) {
    const int row = blockIdx.x * 4 + (threadIdx.x >> 6);
    const int lane = threadIdx.x & 63;
    const size_t base = (size_t)row * 768;
    float v[12];
    float s = 0.f;
#pragma unroll
    for (int i = 0; i < 3; i++) {
        int c = lane * 4 + i * 256;
        uint2 av = *reinterpret_cast<const uint2*>(a + base + c);
        float rv0, rv1, rv2, rv3;
        if (RESF32) {
            float4 r4 = *reinterpret_cast<const float4*>((const float*)res + base + c);
            rv0 = r4.x; rv1 = r4.y; rv2 = r4.z; rv3 = r4.w;
        } else {
            uint2 r2 = *reinterpret_cast<const uint2*>((const u16*)res + base + c);
            rv0 = bl(r2.x); rv1 = bh(r2.x); rv2 = bl(r2.y); rv3 = bh(r2.y);
        }
        v[i * 4 + 0] = bl(av.x) + rv0;
        v[i * 4 + 1] = bh(av.x) + rv1;
        v[i * 4 + 2] = bl(av.y) + rv2;
        v[i * 4 + 3] = bh(av.y) + rv3;
        s += v[i * 4 + 0] + v[i * 4 + 1] + v[i * 4 + 2] + v[i * 4 + 3];
    }
#pragma unroll
    for (int o = 1; o < 64; o <<= 1) s += __shfl_xor(s, o);
    float mean = s * (1.f / 768.f);
    float q = 0.f;
#pragma unroll
    for (int i = 0; i < 12; i++) {
        float d = v[i] - mean;
        q += d * d;
    }
#pragma unroll
    for (int o = 1; o < 64; o <<= 1) q += __shfl_xor(q, o);
    float inv = rsqrtf(q * (1.f / 768.f) + 1e-12f);
#pragma unroll
    for (int i = 0; i < 3; i++) {
        int c = lane * 4 + i * 256;
        float4 g4 = *reinterpret_cast<const float4*>(g + c);
        float4 b4 = *reinterpret_cast<const float4*>(be + c);
        float y0 = (v[i * 4 + 0] - mean) * inv * g4.x + b4.x;
        float y1 = (v[i * 4 + 1] - mean) * inv * g4.y + b4.y;
        float y2 = (v[i * 4 + 2] - mean) * inv * g4.z + b4.z;
        float y3 = (v[i * 4 + 3] - mean) * inv * g4.w + b4.w;
        if (OUTF32) {
            float4 o4 = {y0, y1, y2, y3};
            *reinterpret_cast<float4*>(of + base + c) = o4;
        }
        uint2 ob2;
        ob2.x = pack2(y0, y1);
        ob2.y = pack2(y2, y3);
        *reinterpret_cast<uint2*>(ob + base + c) = ob2;
    }
}

// ---------------- halo block attention (MFMA) ----------------
// Q, K, V all row-major [B*S][768] bf16. V transposed into LDS at stage time.
__global__ __launch_bounds__(256) void attn_mfma(const u16* __restrict__ Q,
                                                 const u16* __restrict__ Kx,
                                                 const u16* __restrict__ Vx,
                                                 u16* __restrict__ Ctx) {
    __shared__ u16 sm0[128 * 104];  // P (padded stride 104); also K [192][64] swizzled
    __shared__ u16 sm1[64 * 192];   // V^T [64 feat][192 tok] chunk-swizzled
    u16* Ks = sm0;
    u16* Ps = sm0;
    u16* Vs = sm1;

    const int bid = blockIdx.x;
    const int h = bid % HH;
    const int n = (bid / HH) % NBLK;
    const int b = bid / (HH * NBLK);
    const int tid = threadIdx.x;
    const int lane = tid & 63, w = tid >> 6;
    const int lr = lane & 15, ls = lane >> 4;
    const int s0 = n * 128 - 32;

#pragma unroll
    for (int j = 0; j < 6; j++) {
        int r = (tid >> 3) + j * 32;
        int c = tid & 7;
        int s = min(max(s0 + r, 0), SS - 1);
        uint4 kv = *reinterpret_cast<const uint4*>(Kx + ((size_t)(b * SS + s)) * 768 + h * 64 + c * 8);
        int byteo = r * 128 + ((c * 16) ^ ((r & 7) << 4));
        *reinterpret_cast<uint4*>(Ks + (byteo >> 1)) = kv;
    }
#pragma unroll
    for (int j = 0; j < 6; j++) {
        int r = (tid >> 3) + j * 32;          // window token
        int c = tid & 7;                      // feature chunk (8 features)
        int s = min(max(s0 + r, 0), SS - 1);
        uint4 vv = *reinterpret_cast<const uint4*>(Vx + ((size_t)(b * SS + s)) * 768 + h * 64 + c * 8);
        const u16* e = reinterpret_cast<const u16*>(&vv);
        int chunk = r >> 3;
        int bo = (r & 7) * 2;
#pragma unroll
        for (int i = 0; i < 8; i++) {
            int d = c * 8 + i;
            int pch = chunk ^ (d & 7) ^ ((d >> 3) & 7);
            Vs[(d * 384 + pch * 16 + bo) >> 1] = e[i];
        }
    }
    __syncthreads();

    const int qrow0 = b * SS + n * 128 + w * 32;
    U16x8 qf[2][2];
#pragma unroll
    for (int mi = 0; mi < 2; mi++)
#pragma unroll
        for (int ks = 0; ks < 2; ks++)
            qf[mi][ks].u = *reinterpret_cast<const uint4*>(
                Q + (size_t)(qrow0 + mi * 16 + lr) * 768 + h * 64 + ks * 32 + ls * 8);

    f32x4 sc[2][12];
#pragma unroll
    for (int mi = 0; mi < 2; mi++)
#pragma unroll
        for (int jt = 0; jt < 12; jt++) sc[mi][jt] = (f32x4){0.f, 0.f, 0.f, 0.f};
#pragma unroll
    for (int jt = 0; jt < 12; jt++) {
        U16x8 kf[2];
#pragma unroll
        for (int ks = 0; ks < 2; ks++) {
            int r = jt * 16 + lr;
            int byteo = r * 128 + ((ks * 64 + ls * 16) ^ ((r & 7) << 4));
            kf[ks].u = *reinterpret_cast<const uint4*>(Ks + (byteo >> 1));
        }
#pragma unroll
        for (int mi = 0; mi < 2; mi++)
#pragma unroll
            for (int ks = 0; ks < 2; ks++)
                sc[mi][jt] = __builtin_amdgcn_mfma_f32_16x16x32_bf16(
                    qf[mi][ks].s, kf[ks].s, sc[mi][jt], 0, 0, 0);
    }

    const int lo = (n == 0) ? 32 : 0;
    const int hi = (n == NBLK - 1) ? 160 : 192;
    float mx[2][4], sm[2][4], inv[2][4];
#pragma unroll
    for (int mi = 0; mi < 2; mi++)
#pragma unroll
        for (int r = 0; r < 4; r++) { mx[mi][r] = -3.0e38f; sm[mi][r] = 0.f; }
#pragma unroll
    for (int jt = 0; jt < 12; jt++) {
        int col = jt * 16 + lr;
        bool valid = (col >= lo) && (col < hi);
#pragma unroll
        for (int mi = 0; mi < 2; mi++)
#pragma unroll
            for (int r = 0; r < 4; r++) {
                float v = valid ? sc[mi][jt][r] * 0.125f : -3.0e38f;
                sc[mi][jt][r] = v;
                mx[mi][r] = fmaxf(mx[mi][r], v);
            }
    }
#pragma unroll
    for (int o = 1; o <= 8; o <<= 1)
#pragma unroll
        for (int mi = 0; mi < 2; mi++)
#pragma unroll
            for (int r = 0; r < 4; r++)
                mx[mi][r] = fmaxf(mx[mi][r], __shfl_xor(mx[mi][r], o));
#pragma unroll
    for (int jt = 0; jt < 12; jt++)
#pragma unroll
        for (int mi = 0; mi < 2; mi++)
#pragma unroll
            for (int r = 0; r < 4; r++) {
                float p = __expf(sc[mi][jt][r] - mx[mi][r]);
                sc[mi][jt][r] = p;
                sm[mi][r] += p;
            }
#pragma unroll
    for (int o = 1; o <= 8; o <<= 1)
#pragma unroll
        for (int mi = 0; mi < 2; mi++)
#pragma unroll
            for (int r = 0; r < 4; r++)
                sm[mi][r] += __shfl_xor(sm[mi][r], o);
#pragma unroll
    for (int mi = 0; mi < 2; mi++)
#pragma unroll
        for (int r = 0; r < 4; r++) inv[mi][r] = 1.0f / sm[mi][r];

    f32x4 oacc[2][4];
#pragma unroll
    for (int mi = 0; mi < 2; mi++)
#pragma unroll
        for (int dt = 0; dt < 4; dt++) oacc[mi][dt] = (f32x4){0.f, 0.f, 0.f, 0.f};
    __syncthreads();

#pragma unroll
    for (int ph = 0; ph < 2; ph++) {
#pragma unroll
        for (int jj = 0; jj < 6; jj++) {
            int jt = ph * 6 + jj;
#pragma unroll
            for (int mi = 0; mi < 2; mi++) {
                int row = w * 32 + mi * 16 + ls * 4;
#pragma unroll
                for (int r = 0; r < 4; r++)
                    Ps[(row + r) * 104 + jj * 16 + lr] = f2b(sc[mi][jt][r]);
            }
        }
        __syncthreads();
#pragma unroll
        for (int kk = 0; kk < 3; kk++) {
            U16x8 pf[2], vf[4];
#pragma unroll
            for (int mi = 0; mi < 2; mi++)
                pf[mi].u = *reinterpret_cast<const uint4*>(
                    Ps + (w * 32 + mi * 16 + lr) * 104 + kk * 32 + ls * 8);
#pragma unroll
            for (int dt = 0; dt < 4; dt++) {
                int rrow = dt * 16 + lr;
                int lch = ph * 12 + kk * 4 + ls;
                int pch = lch ^ (rrow & 7) ^ ((rrow >> 3) & 7);
                vf[dt].u = *reinterpret_cast<const uint4*>(Vs + ((rrow * 384 + pch * 16) >> 1));
            }
#pragma unroll
            for (int mi = 0; mi < 2; mi++)
#pragma unroll
                for (int dt = 0; dt < 4; dt++)
                    oacc[mi][dt] = __builtin_amdgcn_mfma_f32_16x16x32_bf16(
                        pf[mi].s, vf[dt].s, oacc[mi][dt], 0, 0, 0);
        }
        __syncthreads();
    }

#pragma unroll
    for (int mi = 0; mi < 2; mi++)
#pragma unroll
        for (int dt = 0; dt < 4; dt++)
#pragma unroll
            for (int r = 0; r < 4; r++) {
                float v = oacc[mi][dt][r] * inv[mi][r];
                Ctx[(size_t)(qrow0 + mi * 16 + ls * 4 + r) * 768 + h * 64 + dt * 16 + lr] = f2b(v);
            }
}

extern "C" void kernel_launch(void* const* d_in, const int* in_sizes, int n_in,
                              void* d_out, int out_size, void* d_ws, size_t ws_size,
                              hipStream_t stream) {
    (void)in_sizes; (void)n_in; (void)out_size; (void)ws_size;
    const float* x    = (const float*)d_in[0];
    const float* Wq   = (const float*)d_in[1];
    const float* bq   = (const float*)d_in[2];
    const float* Wk   = (const float*)d_in[3];
    const float* bk   = (const float*)d_in[4];
    const float* Wv   = (const float*)d_in[5];
    const float* bv   = (const float*)d_in[6];
    const float* Wo   = (const float*)d_in[7];
    const float* bo   = (const float*)d_in[8];
    const float* ln1g = (const float*)d_in[9];
    const float* ln1b = (const float*)d_in[10];
    const float* W1   = (const float*)d_in[11];
    const float* b1   = (const float*)d_in[12];
    const float* W2   = (const float*)d_in[13];
    const float* b2   = (const float*)d_in[14];
    const float* ln2g = (const float*)d_in[15];
    const float* ln2b = (const float*)d_in[16];
    float* out = (float*)d_out;

    char* ws = (char*)d_ws;
    size_t off = 0;
    auto alloc = [&](size_t bytes) -> char* {
        char* p = ws + off;
        off += (bytes + 255) & ~(size_t)255;
        return p;
    };
    u16* WqkvT = (u16*)alloc(2 * 3 * D2 * sizeof(u16));  // per layer: [Q;K;V] rows
    u16* WoT   = (u16*)alloc(2 * D2 * sizeof(u16));
    u16* W1T   = (u16*)alloc(2 * DI * sizeof(u16));
    u16* W2T   = (u16*)alloc(2 * DI * sizeof(u16));
    u16* Xb    = (u16*)alloc(AD * sizeof(u16));
    u16* RegA  = (u16*)alloc(4 * AD * sizeof(u16)); // Qb,Kb,Vb,Ctxb; reused as H1b
    u16*   AttnB = (u16*)alloc(AD * sizeof(u16));
    u16*   H2b   = (u16*)alloc(AD * sizeof(u16));
    u16* Qb = RegA;
    u16* Kb = RegA + AD;
    u16* Vb = RegA + 2 * AD;    // row-major like Q/K
    u16* Ctxb = RegA + 3 * AD;
    u16* H1b = RegA;

    {
        int nelem = ROWS * DD;
        cast_bf16<<<dim3(nelem / 4 / 256), dim3(256), 0, stream>>>(x, Xb, nelem);
    }
    for (int l = 0; l < 2; l++) {
        u16* base = WqkvT + (size_t)l * 3 * D2;
        cast_transpose<<<dim3(24, 24), dim3(32, 8), 0, stream>>>(Wq + l * D2, base, 768, 768);
        cast_transpose<<<dim3(24, 24), dim3(32, 8), 0, stream>>>(Wk + l * D2, base + D2, 768, 768);
        cast_transpose<<<dim3(24, 24), dim3(32, 8), 0, stream>>>(Wv + l * D2, base + 2 * D2, 768, 768);
        cast_transpose<<<dim3(24, 24), dim3(32, 8), 0, stream>>>(Wo + l * D2, WoT + l * D2, 768, 768);
        cast_transpose<<<dim3(96, 24), dim3(32, 8), 0, stream>>>(W1 + l * DI, W1T + l * DI, 768, 3072);
        cast_transpose<<<dim3(24, 96), dim3(32, 8), 0, stream>>>(W2 + l * DI, W2T + l * DI, 3072, 768);
    }

    const size_t LDSB = 32768;
    const float* xres = x;
    for (int l = 0; l < 2; l++) {
        // fused QKV: N=2304 (bands Q|K|V), all outputs row-major bf16
        gemm128<5><<<dim3(128 * 18), 256, LDSB, stream>>>(
            Xb, WqkvT + (size_t)l * 3 * D2, bq + l * 768, bk + l * 768, bv + l * 768,
            Qb, Kb, Vb, ROWS, 2304, 768, 18);
        attn_mfma<<<dim3(BB * NBLK * HH), 256, 0, stream>>>(Qb, Kb, Vb, Ctxb);
        gemm128<0><<<dim3(128 * 6), 256, LDSB, stream>>>(
            Ctxb, WoT + l * D2, bo + l * 768, nullptr, nullptr,
            H2b, nullptr, nullptr, ROWS, 768, 768, 6);
        // LN1: bf16 GEMM out + f32 residual -> bf16 attn_out (no f32 copy)
        resid_ln2<true, false><<<dim3(ROWS / 4), 256, 0, stream>>>(
            H2b, (const void*)xres, ln1g + l * 768, ln1b + l * 768, nullptr, AttnB);
        gemm128<2><<<dim3(128 * 24), 256, LDSB, stream>>>(
            AttnB, W1T + l * DI, b1 + l * 3072, nullptr, nullptr,
            H1b, nullptr, nullptr, ROWS, 3072, 768, 24);
        gemm128<0><<<dim3(128 * 6), 256, LDSB, stream>>>(
            H1b, W2T + l * DI, b2 + l * 768, nullptr, nullptr,
            H2b, nullptr, nullptr, ROWS, 768, 3072, 6);
        float* outl = out + (size_t)l * AD;
        // LN2: bf16 GEMM out + bf16 attn_out residual -> f32 layer out + bf16 next-X
        resid_ln2<false, true><<<dim3(ROWS / 4), 256, 0, stream>>>(
            H2b, (const void*)AttnB, ln2g + l * 768, ln2b + l * 768, outl, Xb);
        xres = outl;
    }
}

// Round 17
// 820.439 us; speedup vs baseline: 1.4654x; 1.0568x over previous
//
#include <hip/hip_runtime.h>
#include <hip/hip_bf16.h>

typedef unsigned short u16;
typedef unsigned int u32;

static const int DD = 768;
static const int SS = 2048;
static const int BB = 8;
static const int HH = 12;
static const int NBLK = 16;   // S / 128
static const int ROWS = BB * SS;          // 16384
static const size_t AD = (size_t)ROWS * DD;   // activation element count
static const size_t D2 = (size_t)DD * DD;
static const size_t DI = (size_t)DD * 3072;

typedef __attribute__((ext_vector_type(8))) short short8;
typedef __attribute__((ext_vector_type(4))) float f32x4;

union U16x8 { uint4 u; short8 s; };

__device__ __forceinline__ float bl(u32 u) { return __uint_as_float(u << 16); }
__device__ __forceinline__ float bh(u32 u) { return __uint_as_float(u & 0xffff0000u); }
__device__ __forceinline__ u16 f2b(float f) {
    u32 u = __float_as_uint(f);
    u += 0x7fffu + ((u >> 16) & 1u);
    return (u16)(u >> 16);
}
__device__ __forceinline__ u32 pack2(float lo, float hi) {
    return (u32)f2b(lo) | ((u32)f2b(hi) << 16);
}

// async global->LDS, 16B per lane (dest is wave-uniform base + lane*16)
__device__ __forceinline__ void gload16(const u16* g, u16* l) {
    __builtin_amdgcn_global_load_lds(
        (const __attribute__((address_space(1))) void*)g,
        (__attribute__((address_space(3))) void*)l, 16, 0, 0);
}

// fast GELU (tanh form): v * sigmoid(2z), z = 0.7978845608(v + 0.044715 v^3)
__device__ __forceinline__ float gelu_fast(float v) {
    float z2 = 1.5957691216f * (v + 0.044715f * v * v * v);
    z2 = fminf(z2, 80.f);
    float e = __expf(z2);
    return v * (e / (e + 1.0f));
}

// ---------------- elementwise f32 -> bf16 cast ----------------
__global__ __launch_bounds__(256) void cast_bf16(const float* __restrict__ x,
                                                 u16* __restrict__ xb, int n) {
    int i = (blockIdx.x * 256 + threadIdx.x) * 4;
    if (i < n) {
        float4 v = *reinterpret_cast<const float4*>(x + i);
        uint2 p;
        p.x = pack2(v.x, v.y);
        p.y = pack2(v.z, v.w);
        *reinterpret_cast<uint2*>(xb + i) = p;
    }
}

// ---------------- cast + transpose: W[K,N] f32 -> WT[N,K] bf16 ----------------
__global__ __launch_bounds__(256) void cast_transpose(const float* __restrict__ W,
                                                      u16* __restrict__ WT,
                                                      int K, int N) {
    __shared__ float tile[32][33];
    int bx = blockIdx.x;  // along N
    int by = blockIdx.y;  // along K
    int tx = threadIdx.x; // 0..31
    int ty = threadIdx.y; // 0..7
#pragma unroll
    for (int i = 0; i < 4; i++) {
        int kr = by * 32 + ty + i * 8;
        tile[ty + i * 8][tx] = W[(size_t)kr * N + bx * 32 + tx];
    }
    __syncthreads();
#pragma unroll
    for (int i = 0; i < 4; i++) {
        int nr = bx * 32 + ty + i * 8;
        WT[(size_t)nr * K + by * 32 + tx] = f2b(tile[tx][ty + i * 8]);
    }
}

// ---------------- 128x128 MFMA GEMM, BK=32 dbuf, 4 blocks/CU, unroll x2 ------
// r14 configuration restored (session best, 823us). r16 A/B proved the
// chunked XCD swizzle is a WIN here (+5% total): consecutive tn-blocks share
// the A M-panel and the swizzle keeps them on one XCD -> panel L2-hot
// (removal pushed FETCH 90->108MB and cost 44us total).
// EPI 0: bf16 out; 2: gelu->bf16 out; 5: QKV row-major (band uniform/block)
// LDS swizzle (rule #21, both sides): 16B-slot phys = logical ^ ((row>>1)&3).
// Requires NT = K/32 even (call sites: 24, 96).
template <int EPI>
__global__ __launch_bounds__(256, 4) void gemm128(const u16* __restrict__ A,
                                                  const u16* __restrict__ BT,
                                                  const float* __restrict__ b0,
                                                  const float* __restrict__ b1,
                                                  const float* __restrict__ b2,
                                                  void* __restrict__ C0,
                                                  void* __restrict__ C1,
                                                  void* __restrict__ C2,
                                                  int M, int N, int K, int NTN) {
    extern __shared__ u16 smem[];  // 2 slots x 8192 u16 (16KB) = 32KB
    const int tid = threadIdx.x;
    const int nwg = gridDim.x;
    int wg = blockIdx.x;
    // chunked bijective XCD swizzle (all grids divisible by 8)
    wg = (wg & 7) * (nwg >> 3) + (wg >> 3);
    const int tn = wg % NTN, tm = wg / NTN;   // row-major: A M-panel stays hot
    const int m0 = tm * 128, n0 = tn * 128;
    const int lane = tid & 63, w = tid >> 6;
    const int wr = w >> 1, wc = w & 1;
    const int lr = lane & 15, ls = lane >> 4;
    const int sl = ls ^ ((lr >> 1) & 3);      // 2-way-optimal swizzled slot

    const int r3 = tid >> 2, c2 = tid & 3;
    const int kswz = ((c2 ^ ((r3 >> 1) & 3)) << 3);  // pre-swizzled src k-offset
    const u16* sA = A + (size_t)(m0 + r3) * K + kswz;   // incremental sources
    const u16* sB = BT + (size_t)(n0 + r3) * K + kswz;
    const size_t rstep = (size_t)64 * K;       // 64 rows per chunk

    f32x4 acc[4][4];
#pragma unroll
    for (int i = 0; i < 4; i++)
#pragma unroll
        for (int j = 0; j < 4; j++) acc[i][j] = (f32x4){0.f, 0.f, 0.f, 0.f};

#define STAGE_SLOT(SLOT)                                                      \
    {                                                                         \
        u16* pA = smem + (SLOT) * 8192 + tid * 8;                             \
        u16* pB = smem + (SLOT) * 8192 + 4096 + tid * 8;                      \
        gload16(sA, pA);                                                      \
        gload16(sA + rstep, pA + 2048);                                       \
        gload16(sB, pB);                                                      \
        gload16(sB + rstep, pB + 2048);                                       \
        sA += 32;                                                             \
        sB += 32;                                                             \
    }
#define COMPUTE_SLOT(SLOT)                                                    \
    {                                                                         \
        const u16* bufA = smem + (SLOT) * 8192 + (wr * 64 + lr) * 32;         \
        const u16* bufB = smem + (SLOT) * 8192 + 4096 + (wc * 64 + lr) * 32;  \
        U16x8 af[4], bf[4];                                                   \
        _Pragma("unroll") for (int ni = 0; ni < 4; ni++)                      \
            bf[ni].u = *(const uint4*)(bufB + ni * 512 + sl * 8);             \
        _Pragma("unroll") for (int mi = 0; mi < 4; mi++)                      \
            af[mi].u = *(const uint4*)(bufA + mi * 512 + sl * 8);             \
        _Pragma("unroll") for (int mi = 0; mi < 4; mi++)                      \
            _Pragma("unroll") for (int ni = 0; ni < 4; ni++)                  \
                acc[mi][ni] = __builtin_amdgcn_mfma_f32_16x16x32_bf16(        \
                    af[mi].s, bf[ni].s, acc[mi][ni], 0, 0, 0);                \
    }

    const int NT = K >> 5;   // even at all call sites
    STAGE_SLOT(0)            // prologue: tile 0 -> slot 0
    __syncthreads();

    for (int t = 0; t < NT; t += 2) {
        if (t + 1 < NT) STAGE_SLOT(1)   // prefetch tile t+1
        COMPUTE_SLOT(0)                 // compute tile t
        __syncthreads();
        if (t + 2 < NT) STAGE_SLOT(0)   // prefetch tile t+2
        COMPUTE_SLOT(1)                 // compute tile t+1
        __syncthreads();
    }
#undef STAGE_SLOT
#undef COMPUTE_SLOT

    // epilogue
    u16* dstQ = (u16*)C0;
    const float* bp = b0;
    int cbase = 0;
    if (EPI == 5) {                    // band uniform per block (768 % 128 == 0)
        int band = n0 / 768;
        dstQ = (band == 0) ? (u16*)C0 : (band == 1) ? (u16*)C1 : (u16*)C2;
        bp = (band == 0) ? b0 : (band == 1) ? b1 : b2;
        cbase = n0 - band * 768;
    }
#pragma unroll
    for (int mi = 0; mi < 4; mi++) {
        int row0 = m0 + wr * 64 + mi * 16 + ls * 4;
#pragma unroll
        for (int ni = 0; ni < 4; ni++) {
            int cloc = wc * 64 + ni * 16 + lr;
            float v[4];
            if (EPI == 5) {
                float bs = bp[cbase + cloc];
#pragma unroll
                for (int r = 0; r < 4; r++) {
                    v[r] = acc[mi][ni][r] + bs;
                    dstQ[(size_t)(row0 + r) * 768 + cbase + cloc] = f2b(v[r]);
                }
            } else {
                int col = n0 + cloc;
                float bs = b0[col];
#pragma unroll
                for (int r = 0; r < 4; r++) {
                    v[r] = acc[mi][ni][r] + bs;
                    if (EPI == 2) v[r] = gelu_fast(v[r]);
                    ((u16*)C0)[(size_t)(row0 + r) * N + col] = f2b(v[r]);
                }
            }
        }
    }
}

// ------- residual add + LayerNorm, wave-per-row (no LDS, no barriers) -------
// a: bf16 [rows][768]; res: f32 or bf16; writes bf16 ob and optionally f32 of.
// 4 rows per 256-thread block; lane handles 12 elems (3 x 4 at stride 256).
template <bool RESF32, bool OUTF32>
__global__ __launch_bounds__(256) void resid_ln2(const u16* __restrict__ a,
                                                 const void* __restrict__ res,
                                                 const float* __restrict__ g,
                                                 const float* __restrict__ be,
                                                 float* __restrict__ of,
                                                 u16* __restrict__ ob) {
    const int row = blockIdx.x * 4 + (threadIdx.x >> 6);
    const int lane = threadIdx.x & 63;
    const size_t base = (size_t)row * 768;
    float v[12];
    float s = 0.f;
#pragma unroll
    for (int i = 0; i < 3; i++) {
        int c = lane * 4 + i * 256;
        uint2 av = *reinterpret_cast<const uint2*>(a + base + c);
        float rv0, rv1, rv2, rv3;
        if (RESF32) {
            float4 r4 = *reinterpret_cast<const float4*>((const float*)res + base + c);
            rv0 = r4.x; rv1 = r4.y; rv2 = r4.z; rv3 = r4.w;
        } else {
            uint2 r2 = *reinterpret_cast<const uint2*>((const u16*)res + base + c);
            rv0 = bl(r2.x); rv1 = bh(r2.x); rv2 = bl(r2.y); rv3 = bh(r2.y);
        }
        v[i * 4 + 0] = bl(av.x) + rv0;
        v[i * 4 + 1] = bh(av.x) + rv1;
        v[i * 4 + 2] = bl(av.y) + rv2;
        v[i * 4 + 3] = bh(av.y) + rv3;
        s += v[i * 4 + 0] + v[i * 4 + 1] + v[i * 4 + 2] + v[i * 4 + 3];
    }
#pragma unroll
    for (int o = 1; o < 64; o <<= 1) s += __shfl_xor(s, o);
    float mean = s * (1.f / 768.f);
    float q = 0.f;
#pragma unroll
    for (int i = 0; i < 12; i++) {
        float d = v[i] - mean;
        q += d * d;
    }
#pragma unroll
    for (int o = 1; o < 64; o <<= 1) q += __shfl_xor(q, o);
    float inv = rsqrtf(q * (1.f / 768.f) + 1e-12f);
#pragma unroll
    for (int i = 0; i < 3; i++) {
        int c = lane * 4 + i * 256;
        float4 g4 = *reinterpret_cast<const float4*>(g + c);
        float4 b4 = *reinterpret_cast<const float4*>(be + c);
        float y0 = (v[i * 4 + 0] - mean) * inv * g4.x + b4.x;
        float y1 = (v[i * 4 + 1] - mean) * inv * g4.y + b4.y;
        float y2 = (v[i * 4 + 2] - mean) * inv * g4.z + b4.z;
        float y3 = (v[i * 4 + 3] - mean) * inv * g4.w + b4.w;
        if (OUTF32) {
            float4 o4 = {y0, y1, y2, y3};
            *reinterpret_cast<float4*>(of + base + c) = o4;
        }
        uint2 ob2;
        ob2.x = pack2(y0, y1);
        ob2.y = pack2(y2, y3);
        *reinterpret_cast<uint2*>(ob + base + c) = ob2;
    }
}

// ---------------- halo block attention (MFMA) ----------------
// Q, K, V all row-major [B*S][768] bf16. V transposed into LDS at stage time.
__global__ __launch_bounds__(256) void attn_mfma(const u16* __restrict__ Q,
                                                 const u16* __restrict__ Kx,
                                                 const u16* __restrict__ Vx,
                                                 u16* __restrict__ Ctx) {
    __shared__ u16 sm0[128 * 104];  // P (padded stride 104); also K [192][64] swizzled
    __shared__ u16 sm1[64 * 192];   // V^T [64 feat][192 tok] chunk-swizzled
    u16* Ks = sm0;
    u16* Ps = sm0;
    u16* Vs = sm1;

    const int bid = blockIdx.x;
    const int h = bid % HH;
    const int n = (bid / HH) % NBLK;
    const int b = bid / (HH * NBLK);
    const int tid = threadIdx.x;
    const int lane = tid & 63, w = tid >> 6;
    const int lr = lane & 15, ls = lane >> 4;
    const int s0 = n * 128 - 32;

#pragma unroll
    for (int j = 0; j < 6; j++) {
        int r = (tid >> 3) + j * 32;
        int c = tid & 7;
        int s = min(max(s0 + r, 0), SS - 1);
        uint4 kv = *reinterpret_cast<const uint4*>(Kx + ((size_t)(b * SS + s)) * 768 + h * 64 + c * 8);
        int byteo = r * 128 + ((c * 16) ^ ((r & 7) << 4));
        *reinterpret_cast<uint4*>(Ks + (byteo >> 1)) = kv;
    }
#pragma unroll
    for (int j = 0; j < 6; j++) {
        int r = (tid >> 3) + j * 32;          // window token
        int c = tid & 7;                      // feature chunk (8 features)
        int s = min(max(s0 + r, 0), SS - 1);
        uint4 vv = *reinterpret_cast<const uint4*>(Vx + ((size_t)(b * SS + s)) * 768 + h * 64 + c * 8);
        const u16* e = reinterpret_cast<const u16*>(&vv);
        int chunk = r >> 3;
        int bo = (r & 7) * 2;
#pragma unroll
        for (int i = 0; i < 8; i++) {
            int d = c * 8 + i;
            int pch = chunk ^ (d & 7) ^ ((d >> 3) & 7);
            Vs[(d * 384 + pch * 16 + bo) >> 1] = e[i];
        }
    }
    __syncthreads();

    const int qrow0 = b * SS + n * 128 + w * 32;
    U16x8 qf[2][2];
#pragma unroll
    for (int mi = 0; mi < 2; mi++)
#pragma unroll
        for (int ks = 0; ks < 2; ks++)
            qf[mi][ks].u = *reinterpret_cast<const uint4*>(
                Q + (size_t)(qrow0 + mi * 16 + lr) * 768 + h * 64 + ks * 32 + ls * 8);

    f32x4 sc[2][12];
#pragma unroll
    for (int mi = 0; mi < 2; mi++)
#pragma unroll
        for (int jt = 0; jt < 12; jt++) sc[mi][jt] = (f32x4){0.f, 0.f, 0.f, 0.f};
#pragma unroll
    for (int jt = 0; jt < 12; jt++) {
        U16x8 kf[2];
#pragma unroll
        for (int ks = 0; ks < 2; ks++) {
            int r = jt * 16 + lr;
            int byteo = r * 128 + ((ks * 64 + ls * 16) ^ ((r & 7) << 4));
            kf[ks].u = *reinterpret_cast<const uint4*>(Ks + (byteo >> 1));
        }
#pragma unroll
        for (int mi = 0; mi < 2; mi++)
#pragma unroll
            for (int ks = 0; ks < 2; ks++)
                sc[mi][jt] = __builtin_amdgcn_mfma_f32_16x16x32_bf16(
                    qf[mi][ks].s, kf[ks].s, sc[mi][jt], 0, 0, 0);
    }

    const int lo = (n == 0) ? 32 : 0;
    const int hi = (n == NBLK - 1) ? 160 : 192;
    float mx[2][4], sm[2][4], inv[2][4];
#pragma unroll
    for (int mi = 0; mi < 2; mi++)
#pragma unroll
        for (int r = 0; r < 4; r++) { mx[mi][r] = -3.0e38f; sm[mi][r] = 0.f; }
#pragma unroll
    for (int jt = 0; jt < 12; jt++) {
        int col = jt * 16 + lr;
        bool valid = (col >= lo) && (col < hi);
#pragma unroll
        for (int mi = 0; mi < 2; mi++)
#pragma unroll
            for (int r = 0; r < 4; r++) {
                float v = valid ? sc[mi][jt][r] * 0.125f : -3.0e38f;
                sc[mi][jt][r] = v;
                mx[mi][r] = fmaxf(mx[mi][r], v);
            }
    }
#pragma unroll
    for (int o = 1; o <= 8; o <<= 1)
#pragma unroll
        for (int mi = 0; mi < 2; mi++)
#pragma unroll
            for (int r = 0; r < 4; r++)
                mx[mi][r] = fmaxf(mx[mi][r], __shfl_xor(mx[mi][r], o));
#pragma unroll
    for (int jt = 0; jt < 12; jt++)
#pragma unroll
        for (int mi = 0; mi < 2; mi++)
#pragma unroll
            for (int r = 0; r < 4; r++) {
                float p = __expf(sc[mi][jt][r] - mx[mi][r]);
                sc[mi][jt][r] = p;
                sm[mi][r] += p;
            }
#pragma unroll
    for (int o = 1; o <= 8; o <<= 1)
#pragma unroll
        for (int mi = 0; mi < 2; mi++)
#pragma unroll
            for (int r = 0; r < 4; r++)
                sm[mi][r] += __shfl_xor(sm[mi][r], o);
#pragma unroll
    for (int mi = 0; mi < 2; mi++)
#pragma unroll
        for (int r = 0; r < 4; r++) inv[mi][r] = 1.0f / sm[mi][r];

    f32x4 oacc[2][4];
#pragma unroll
    for (int mi = 0; mi < 2; mi++)
#pragma unroll
        for (int dt = 0; dt < 4; dt++) oacc[mi][dt] = (f32x4){0.f, 0.f, 0.f, 0.f};
    __syncthreads();

#pragma unroll
    for (int ph = 0; ph < 2; ph++) {
#pragma unroll
        for (int jj = 0; jj < 6; jj++) {
            int jt = ph * 6 + jj;
#pragma unroll
            for (int mi = 0; mi < 2; mi++) {
                int row = w * 32 + mi * 16 + ls * 4;
#pragma unroll
                for (int r = 0; r < 4; r++)
                    Ps[(row + r) * 104 + jj * 16 + lr] = f2b(sc[mi][jt][r]);
            }
        }
        __syncthreads();
#pragma unroll
        for (int kk = 0; kk < 3; kk++) {
            U16x8 pf[2], vf[4];
#pragma unroll
            for (int mi = 0; mi < 2; mi++)
                pf[mi].u = *reinterpret_cast<const uint4*>(
                    Ps + (w * 32 + mi * 16 + lr) * 104 + kk * 32 + ls * 8);
#pragma unroll
            for (int dt = 0; dt < 4; dt++) {
                int rrow = dt * 16 + lr;
                int lch = ph * 12 + kk * 4 + ls;
                int pch = lch ^ (rrow & 7) ^ ((rrow >> 3) & 7);
                vf[dt].u = *reinterpret_cast<const uint4*>(Vs + ((rrow * 384 + pch * 16) >> 1));
            }
#pragma unroll
            for (int mi = 0; mi < 2; mi++)
#pragma unroll
                for (int dt = 0; dt < 4; dt++)
                    oacc[mi][dt] = __builtin_amdgcn_mfma_f32_16x16x32_bf16(
                        pf[mi].s, vf[dt].s, oacc[mi][dt], 0, 0, 0);
        }
        __syncthreads();
    }

#pragma unroll
    for (int mi = 0; mi < 2; mi++)
#pragma unroll
        for (int dt = 0; dt < 4; dt++)
#pragma unroll
            for (int r = 0; r < 4; r++) {
                float v = oacc[mi][dt][r] * inv[mi][r];
                Ctx[(size_t)(qrow0 + mi * 16 + ls * 4 + r) * 768 + h * 64 + dt * 16 + lr] = f2b(v);
            }
}

extern "C" void kernel_launch(void* const* d_in, const int* in_sizes, int n_in,
                              void* d_out, int out_size, void* d_ws, size_t ws_size,
                              hipStream_t stream) {
    (void)in_sizes; (void)n_in; (void)out_size; (void)ws_size;
    const float* x    = (const float*)d_in[0];
    const float* Wq   = (const float*)d_in[1];
    const float* bq   = (const float*)d_in[2];
    const float* Wk   = (const float*)d_in[3];
    const float* bk   = (const float*)d_in[4];
    const float* Wv   = (const float*)d_in[5];
    const float* bv   = (const float*)d_in[6];
    const float* Wo   = (const float*)d_in[7];
    const float* bo   = (const float*)d_in[8];
    const float* ln1g = (const float*)d_in[9];
    const float* ln1b = (const float*)d_in[10];
    const float* W1   = (const float*)d_in[11];
    const float* b1   = (const float*)d_in[12];
    const float* W2   = (const float*)d_in[13];
    const float* b2   = (const float*)d_in[14];
    const float* ln2g = (const float*)d_in[15];
    const float* ln2b = (const float*)d_in[16];
    float* out = (float*)d_out;

    char* ws = (char*)d_ws;
    size_t off = 0;
    auto alloc = [&](size_t bytes) -> char* {
        char* p = ws + off;
        off += (bytes + 255) & ~(size_t)255;
        return p;
    };
    u16* WqkvT = (u16*)alloc(2 * 3 * D2 * sizeof(u16));  // per layer: [Q;K;V] rows
    u16* WoT   = (u16*)alloc(2 * D2 * sizeof(u16));
    u16* W1T   = (u16*)alloc(2 * DI * sizeof(u16));
    u16* W2T   = (u16*)alloc(2 * DI * sizeof(u16));
    u16* Xb    = (u16*)alloc(AD * sizeof(u16));
    u16* RegA  = (u16*)alloc(4 * AD * sizeof(u16)); // Qb,Kb,Vb,Ctxb; reused as H1b
    u16*   AttnB = (u16*)alloc(AD * sizeof(u16));
    u16*   H2b   = (u16*)alloc(AD * sizeof(u16));
    u16* Qb = RegA;
    u16* Kb = RegA + AD;
    u16* Vb = RegA + 2 * AD;    // row-major like Q/K
    u16* Ctxb = RegA + 3 * AD;
    u16* H1b = RegA;

    {
        int nelem = ROWS * DD;
        cast_bf16<<<dim3(nelem / 4 / 256), dim3(256), 0, stream>>>(x, Xb, nelem);
    }
    for (int l = 0; l < 2; l++) {
        u16* base = WqkvT + (size_t)l * 3 * D2;
        cast_transpose<<<dim3(24, 24), dim3(32, 8), 0, stream>>>(Wq + l * D2, base, 768, 768);
        cast_transpose<<<dim3(24, 24), dim3(32, 8), 0, stream>>>(Wk + l * D2, base + D2, 768, 768);
        cast_transpose<<<dim3(24, 24), dim3(32, 8), 0, stream>>>(Wv + l * D2, base + 2 * D2, 768, 768);
        cast_transpose<<<dim3(24, 24), dim3(32, 8), 0, stream>>>(Wo + l * D2, WoT + l * D2, 768, 768);
        cast_transpose<<<dim3(96, 24), dim3(32, 8), 0, stream>>>(W1 + l * DI, W1T + l * DI, 768, 3072);
        cast_transpose<<<dim3(24, 96), dim3(32, 8), 0, stream>>>(W2 + l * DI, W2T + l * DI, 3072, 768);
    }

    const size_t LDSB = 32768;
    const float* xres = x;
    for (int l = 0; l < 2; l++) {
        // fused QKV: N=2304 (bands Q|K|V), all outputs row-major bf16
        gemm128<5><<<dim3(128 * 18), 256, LDSB, stream>>>(
            Xb, WqkvT + (size_t)l * 3 * D2, bq + l * 768, bk + l * 768, bv + l * 768,
            Qb, Kb, Vb, ROWS, 2304, 768, 18);
        attn_mfma<<<dim3(BB * NBLK * HH), 256, 0, stream>>>(Qb, Kb, Vb, Ctxb);
        gemm128<0><<<dim3(128 * 6), 256, LDSB, stream>>>(
            Ctxb, WoT + l * D2, bo + l * 768, nullptr, nullptr,
            H2b, nullptr, nullptr, ROWS, 768, 768, 6);
        // LN1: bf16 GEMM out + f32 residual -> bf16 attn_out (no f32 copy)
        resid_ln2<true, false><<<dim3(ROWS / 4), 256, 0, stream>>>(
            H2b, (const void*)xres, ln1g + l * 768, ln1b + l * 768, nullptr, AttnB);
        gemm128<2><<<dim3(128 * 24), 256, LDSB, stream>>>(
            AttnB, W1T + l * DI, b1 + l * 3072, nullptr, nullptr,
            H1b, nullptr, nullptr, ROWS, 3072, 768, 24);
        gemm128<0><<<dim3(128 * 6), 256, LDSB, stream>>>(
            H1b, W2T + l * DI, b2 + l * 768, nullptr, nullptr,
            H2b, nullptr, nullptr, ROWS, 768, 3072, 6);
        float* outl = out + (size_t)l * AD;
        // LN2: bf16 GEMM out + bf16 attn_out residual -> f32 layer out + bf16 next-X
        resid_ln2<false, true><<<dim3(ROWS / 4), 256, 0, stream>>>(
            H2b, (const void*)AttnB, ln2g + l * 768, ln2b + l * 768, outl, Xb);
        xres = outl;
    }
}

// Round 18
// 805.124 us; speedup vs baseline: 1.4932x; 1.0190x over previous
//
#include <hip/hip_runtime.h>
#include <hip/hip_bf16.h>

typedef unsigned short u16;
typedef unsigned int u32;

static const int DD = 768;
static const int SS = 2048;
static const int BB = 8;
static const int HH = 12;
static const int NBLK = 16;   // S / 128
static const int ROWS = BB * SS;          // 16384
static const size_t AD = (size_t)ROWS * DD;   // activation element count
static const size_t D2 = (size_t)DD * DD;
static const size_t DI = (size_t)DD * 3072;

typedef __attribute__((ext_vector_type(8))) short short8;
typedef __attribute__((ext_vector_type(4))) float f32x4;

union U16x8 { uint4 u; short8 s; };

__device__ __forceinline__ float bl(u32 u) { return __uint_as_float(u << 16); }
__device__ __forceinline__ float bh(u32 u) { return __uint_as_float(u & 0xffff0000u); }
__device__ __forceinline__ u16 f2b(float f) {
    u32 u = __float_as_uint(f);
    u += 0x7fffu + ((u >> 16) & 1u);
    return (u16)(u >> 16);
}
__device__ __forceinline__ u32 pack2(float lo, float hi) {
    return (u32)f2b(lo) | ((u32)f2b(hi) << 16);
}

// async global->LDS, 16B per lane (dest is wave-uniform base + lane*16)
__device__ __forceinline__ void gload16(const u16* g, u16* l) {
    __builtin_amdgcn_global_load_lds(
        (const __attribute__((address_space(1))) void*)g,
        (__attribute__((address_space(3))) void*)l, 16, 0, 0);
}

// fast GELU (tanh form): v * sigmoid(2z), z = 0.7978845608(v + 0.044715 v^3)
__device__ __forceinline__ float gelu_fast(float v) {
    float z2 = 1.5957691216f * (v + 0.044715f * v * v * v);
    z2 = fminf(z2, 80.f);
    float e = __expf(z2);
    return v * (e / (e + 1.0f));
}

// ------------- fused prep: x cast + all 12 weight cast+transposes -------------
// One dispatch replaces 13. Flat grid 26112 blocks:
//   [0, 12288): x f32 -> bf16, 1024 elems/block (exactly ROWS*DD)
//   [12288, 26112): 32x32 cast+transpose tiles; per layer (6912 tiles):
//     [0,2304): Wq/Wk/Wv/Wo (576 tiles each, 768x768)
//     [2304,4608): W1 (768x3072), [4608,6912): W2 (3072x768)
// Branch is uniform per block; pointer selection via if-chain (rule #20).
__global__ __launch_bounds__(256) void prep_all(
    const float* __restrict__ x, u16* __restrict__ xb,
    const float* __restrict__ Wq, const float* __restrict__ Wk,
    const float* __restrict__ Wv, const float* __restrict__ Wo,
    const float* __restrict__ W1, const float* __restrict__ W2,
    u16* __restrict__ WqkvT, u16* __restrict__ WoT,
    u16* __restrict__ W1T, u16* __restrict__ W2T) {
    const int bid = blockIdx.x;
    if (bid < 12288) {
        int i = (bid * 256 + threadIdx.x) * 4;
        float4 v = *reinterpret_cast<const float4*>(x + i);
        uint2 p;
        p.x = pack2(v.x, v.y);
        p.y = pack2(v.z, v.w);
        *reinterpret_cast<uint2*>(xb + i) = p;
        return;
    }
    __shared__ float tile[32][33];
    int t = bid - 12288;
    const int layer = t / 6912;
    int r = t % 6912;
    const float* W;
    u16* WT;
    int K, N, bx, by;
    if (r < 2304) {
        int m = r / 576, tl = r % 576;
        K = 768; N = 768;
        bx = tl % 24; by = tl / 24;
        if (m == 0)      { W = Wq + (size_t)layer * D2; WT = WqkvT + (size_t)layer * 3 * D2; }
        else if (m == 1) { W = Wk + (size_t)layer * D2; WT = WqkvT + (size_t)layer * 3 * D2 + D2; }
        else if (m == 2) { W = Wv + (size_t)layer * D2; WT = WqkvT + (size_t)layer * 3 * D2 + 2 * D2; }
        else             { W = Wo + (size_t)layer * D2; WT = WoT + (size_t)layer * D2; }
    } else if (r < 4608) {
        int tl = r - 2304;
        K = 768; N = 3072;
        bx = tl % 96; by = tl / 96;
        W = W1 + (size_t)layer * DI;
        WT = W1T + (size_t)layer * DI;
    } else {
        int tl = r - 4608;
        K = 3072; N = 768;
        bx = tl % 24; by = tl / 24;
        W = W2 + (size_t)layer * DI;
        WT = W2T + (size_t)layer * DI;
    }
    const int tx = threadIdx.x & 31, ty = threadIdx.x >> 5;
#pragma unroll
    for (int i = 0; i < 4; i++) {
        int kr = by * 32 + ty + i * 8;
        tile[ty + i * 8][tx] = W[(size_t)kr * N + bx * 32 + tx];
    }
    __syncthreads();
#pragma unroll
    for (int i = 0; i < 4; i++) {
        int nr = bx * 32 + ty + i * 8;
        WT[(size_t)nr * K + by * 32 + tx] = f2b(tile[tx][ty + i * 8]);
    }
}

// ---------------- 128x128 MFMA GEMM, BK=32 dbuf, 4 blocks/CU, unroll x2 ------
// r14/r17 configuration (session best, 820us). Chunked XCD swizzle is a WIN
// (+5% total, r16 A/B): consecutive tn-blocks share the A M-panel and the
// swizzle keeps them on one XCD -> panel L2-hot.
// EPI 0: bf16 out; 2: gelu->bf16 out; 5: QKV row-major (band uniform/block)
// LDS swizzle (rule #21, both sides): 16B-slot phys = logical ^ ((row>>1)&3).
// Requires NT = K/32 even (call sites: 24, 96).
template <int EPI>
__global__ __launch_bounds__(256, 4) void gemm128(const u16* __restrict__ A,
                                                  const u16* __restrict__ BT,
                                                  const float* __restrict__ b0,
                                                  const float* __restrict__ b1,
                                                  const float* __restrict__ b2,
                                                  void* __restrict__ C0,
                                                  void* __restrict__ C1,
                                                  void* __restrict__ C2,
                                                  int M, int N, int K, int NTN) {
    extern __shared__ u16 smem[];  // 2 slots x 8192 u16 (16KB) = 32KB
    const int tid = threadIdx.x;
    const int nwg = gridDim.x;
    int wg = blockIdx.x;
    // chunked bijective XCD swizzle (all grids divisible by 8)
    wg = (wg & 7) * (nwg >> 3) + (wg >> 3);
    const int tn = wg % NTN, tm = wg / NTN;   // row-major: A M-panel stays hot
    const int m0 = tm * 128, n0 = tn * 128;
    const int lane = tid & 63, w = tid >> 6;
    const int wr = w >> 1, wc = w & 1;
    const int lr = lane & 15, ls = lane >> 4;
    const int sl = ls ^ ((lr >> 1) & 3);      // 2-way-optimal swizzled slot

    const int r3 = tid >> 2, c2 = tid & 3;
    const int kswz = ((c2 ^ ((r3 >> 1) & 3)) << 3);  // pre-swizzled src k-offset
    const u16* sA = A + (size_t)(m0 + r3) * K + kswz;   // incremental sources
    const u16* sB = BT + (size_t)(n0 + r3) * K + kswz;
    const size_t rstep = (size_t)64 * K;       // 64 rows per chunk

    f32x4 acc[4][4];
#pragma unroll
    for (int i = 0; i < 4; i++)
#pragma unroll
        for (int j = 0; j < 4; j++) acc[i][j] = (f32x4){0.f, 0.f, 0.f, 0.f};

#define STAGE_SLOT(SLOT)                                                      \
    {                                                                         \
        u16* pA = smem + (SLOT) * 8192 + tid * 8;                             \
        u16* pB = smem + (SLOT) * 8192 + 4096 + tid * 8;                      \
        gload16(sA, pA);                                                      \
        gload16(sA + rstep, pA + 2048);                                       \
        gload16(sB, pB);                                                      \
        gload16(sB + rstep, pB + 2048);                                       \
        sA += 32;                                                             \
        sB += 32;                                                             \
    }
#define COMPUTE_SLOT(SLOT)                                                    \
    {                                                                         \
        const u16* bufA = smem + (SLOT) * 8192 + (wr * 64 + lr) * 32;         \
        const u16* bufB = smem + (SLOT) * 8192 + 4096 + (wc * 64 + lr) * 32;  \
        U16x8 af[4], bf[4];                                                   \
        _Pragma("unroll") for (int ni = 0; ni < 4; ni++)                      \
            bf[ni].u = *(const uint4*)(bufB + ni * 512 + sl * 8);             \
        _Pragma("unroll") for (int mi = 0; mi < 4; mi++)                      \
            af[mi].u = *(const uint4*)(bufA + mi * 512 + sl * 8);             \
        _Pragma("unroll") for (int mi = 0; mi < 4; mi++)                      \
            _Pragma("unroll") for (int ni = 0; ni < 4; ni++)                  \
                acc[mi][ni] = __builtin_amdgcn_mfma_f32_16x16x32_bf16(        \
                    af[mi].s, bf[ni].s, acc[mi][ni], 0, 0, 0);                \
    }

    const int NT = K >> 5;   // even at all call sites
    STAGE_SLOT(0)            // prologue: tile 0 -> slot 0
    __syncthreads();

    for (int t = 0; t < NT; t += 2) {
        if (t + 1 < NT) STAGE_SLOT(1)   // prefetch tile t+1
        COMPUTE_SLOT(0)                 // compute tile t
        __syncthreads();
        if (t + 2 < NT) STAGE_SLOT(0)   // prefetch tile t+2
        COMPUTE_SLOT(1)                 // compute tile t+1
        __syncthreads();
    }
#undef STAGE_SLOT
#undef COMPUTE_SLOT

    // epilogue
    u16* dstQ = (u16*)C0;
    const float* bp = b0;
    int cbase = 0;
    if (EPI == 5) {                    // band uniform per block (768 % 128 == 0)
        int band = n0 / 768;
        dstQ = (band == 0) ? (u16*)C0 : (band == 1) ? (u16*)C1 : (u16*)C2;
        bp = (band == 0) ? b0 : (band == 1) ? b1 : b2;
        cbase = n0 - band * 768;
    }
#pragma unroll
    for (int mi = 0; mi < 4; mi++) {
        int row0 = m0 + wr * 64 + mi * 16 + ls * 4;
#pragma unroll
        for (int ni = 0; ni < 4; ni++) {
            int cloc = wc * 64 + ni * 16 + lr;
            float v[4];
            if (EPI == 5) {
                float bs = bp[cbase + cloc];
#pragma unroll
                for (int r = 0; r < 4; r++) {
                    v[r] = acc[mi][ni][r] + bs;
                    dstQ[(size_t)(row0 + r) * 768 + cbase + cloc] = f2b(v[r]);
                }
            } else {
                int col = n0 + cloc;
                float bs = b0[col];
#pragma unroll
                for (int r = 0; r < 4; r++) {
                    v[r] = acc[mi][ni][r] + bs;
                    if (EPI == 2) v[r] = gelu_fast(v[r]);
                    ((u16*)C0)[(size_t)(row0 + r) * N + col] = f2b(v[r]);
                }
            }
        }
    }
}

// ------- residual add + LayerNorm, wave-per-row (no LDS, no barriers) -------
// a: bf16 [rows][768]; res: f32 or bf16; writes bf16 ob and optionally f32 of.
// 4 rows per 256-thread block; lane handles 12 elems (3 x 4 at stride 256).
template <bool RESF32, bool OUTF32>
__global__ __launch_bounds__(256) void resid_ln2(const u16* __restrict__ a,
                                                 const void* __restrict__ res,
                                                 const float* __restrict__ g,
                                                 const float* __restrict__ be,
                                                 float* __restrict__ of,
                                                 u16* __restrict__ ob) {
    const int row = blockIdx.x * 4 + (threadIdx.x >> 6);
    const int lane = threadIdx.x & 63;
    const size_t base = (size_t)row * 768;
    float v[12];
    float s = 0.f;
#pragma unroll
    for (int i = 0; i < 3; i++) {
        int c = lane * 4 + i * 256;
        uint2 av = *reinterpret_cast<const uint2*>(a + base + c);
        float rv0, rv1, rv2, rv3;
        if (RESF32) {
            float4 r4 = *reinterpret_cast<const float4*>((const float*)res + base + c);
            rv0 = r4.x; rv1 = r4.y; rv2 = r4.z; rv3 = r4.w;
        } else {
            uint2 r2 = *reinterpret_cast<const uint2*>((const u16*)res + base + c);
            rv0 = bl(r2.x); rv1 = bh(r2.x); rv2 = bl(r2.y); rv3 = bh(r2.y);
        }
        v[i * 4 + 0] = bl(av.x) + rv0;
        v[i * 4 + 1] = bh(av.x) + rv1;
        v[i * 4 + 2] = bl(av.y) + rv2;
        v[i * 4 + 3] = bh(av.y) + rv3;
        s += v[i * 4 + 0] + v[i * 4 + 1] + v[i * 4 + 2] + v[i * 4 + 3];
    }
#pragma unroll
    for (int o = 1; o < 64; o <<= 1) s += __shfl_xor(s, o);
    float mean = s * (1.f / 768.f);
    float q = 0.f;
#pragma unroll
    for (int i = 0; i < 12; i++) {
        float d = v[i] - mean;
        q += d * d;
    }
#pragma unroll
    for (int o = 1; o < 64; o <<= 1) q += __shfl_xor(q, o);
    float inv = rsqrtf(q * (1.f / 768.f) + 1e-12f);
#pragma unroll
    for (int i = 0; i < 3; i++) {
        int c = lane * 4 + i * 256;
        float4 g4 = *reinterpret_cast<const float4*>(g + c);
        float4 b4 = *reinterpret_cast<const float4*>(be + c);
        float y0 = (v[i * 4 + 0] - mean) * inv * g4.x + b4.x;
        float y1 = (v[i * 4 + 1] - mean) * inv * g4.y + b4.y;
        float y2 = (v[i * 4 + 2] - mean) * inv * g4.z + b4.z;
        float y3 = (v[i * 4 + 3] - mean) * inv * g4.w + b4.w;
        if (OUTF32) {
            float4 o4 = {y0, y1, y2, y3};
            *reinterpret_cast<float4*>(of + base + c) = o4;
        }
        uint2 ob2;
        ob2.x = pack2(y0, y1);
        ob2.y = pack2(y2, y3);
        *reinterpret_cast<uint2*>(ob + base + c) = ob2;
    }
}

// ---------------- halo block attention (MFMA) ----------------
// Q, K, V all row-major [B*S][768] bf16. V transposed into LDS at stage time.
__global__ __launch_bounds__(256) void attn_mfma(const u16* __restrict__ Q,
                                                 const u16* __restrict__ Kx,
                                                 const u16* __restrict__ Vx,
                                                 u16* __restrict__ Ctx) {
    __shared__ u16 sm0[128 * 104];  // P (padded stride 104); also K [192][64] swizzled
    __shared__ u16 sm1[64 * 192];   // V^T [64 feat][192 tok] chunk-swizzled
    u16* Ks = sm0;
    u16* Ps = sm0;
    u16* Vs = sm1;

    const int bid = blockIdx.x;
    const int h = bid % HH;
    const int n = (bid / HH) % NBLK;
    const int b = bid / (HH * NBLK);
    const int tid = threadIdx.x;
    const int lane = tid & 63, w = tid >> 6;
    const int lr = lane & 15, ls = lane >> 4;
    const int s0 = n * 128 - 32;

#pragma unroll
    for (int j = 0; j < 6; j++) {
        int r = (tid >> 3) + j * 32;
        int c = tid & 7;
        int s = min(max(s0 + r, 0), SS - 1);
        uint4 kv = *reinterpret_cast<const uint4*>(Kx + ((size_t)(b * SS + s)) * 768 + h * 64 + c * 8);
        int byteo = r * 128 + ((c * 16) ^ ((r & 7) << 4));
        *reinterpret_cast<uint4*>(Ks + (byteo >> 1)) = kv;
    }
#pragma unroll
    for (int j = 0; j < 6; j++) {
        int r = (tid >> 3) + j * 32;          // window token
        int c = tid & 7;                      // feature chunk (8 features)
        int s = min(max(s0 + r, 0), SS - 1);
        uint4 vv = *reinterpret_cast<const uint4*>(Vx + ((size_t)(b * SS + s)) * 768 + h * 64 + c * 8);
        const u16* e = reinterpret_cast<const u16*>(&vv);
        int chunk = r >> 3;
        int bo = (r & 7) * 2;
#pragma unroll
        for (int i = 0; i < 8; i++) {
            int d = c * 8 + i;
            int pch = chunk ^ (d & 7) ^ ((d >> 3) & 7);
            Vs[(d * 384 + pch * 16 + bo) >> 1] = e[i];
        }
    }
    __syncthreads();

    const int qrow0 = b * SS + n * 128 + w * 32;
    U16x8 qf[2][2];
#pragma unroll
    for (int mi = 0; mi < 2; mi++)
#pragma unroll
        for (int ks = 0; ks < 2; ks++)
            qf[mi][ks].u = *reinterpret_cast<const uint4*>(
                Q + (size_t)(qrow0 + mi * 16 + lr) * 768 + h * 64 + ks * 32 + ls * 8);

    f32x4 sc[2][12];
#pragma unroll
    for (int mi = 0; mi < 2; mi++)
#pragma unroll
        for (int jt = 0; jt < 12; jt++) sc[mi][jt] = (f32x4){0.f, 0.f, 0.f, 0.f};
#pragma unroll
    for (int jt = 0; jt < 12; jt++) {
        U16x8 kf[2];
#pragma unroll
        for (int ks = 0; ks < 2; ks++) {
            int r = jt * 16 + lr;
            int byteo = r * 128 + ((ks * 64 + ls * 16) ^ ((r & 7) << 4));
            kf[ks].u = *reinterpret_cast<const uint4*>(Ks + (byteo >> 1));
        }
#pragma unroll
        for (int mi = 0; mi < 2; mi++)
#pragma unroll
            for (int ks = 0; ks < 2; ks++)
                sc[mi][jt] = __builtin_amdgcn_mfma_f32_16x16x32_bf16(
                    qf[mi][ks].s, kf[ks].s, sc[mi][jt], 0, 0, 0);
    }

    const int lo = (n == 0) ? 32 : 0;
    const int hi = (n == NBLK - 1) ? 160 : 192;
    float mx[2][4], sm[2][4], inv[2][4];
#pragma unroll
    for (int mi = 0; mi < 2; mi++)
#pragma unroll
        for (int r = 0; r < 4; r++) { mx[mi][r] = -3.0e38f; sm[mi][r] = 0.f; }
#pragma unroll
    for (int jt = 0; jt < 12; jt++) {
        int col = jt * 16 + lr;
        bool valid = (col >= lo) && (col < hi);
#pragma unroll
        for (int mi = 0; mi < 2; mi++)
#pragma unroll
            for (int r = 0; r < 4; r++) {
                float v = valid ? sc[mi][jt][r] * 0.125f : -3.0e38f;
                sc[mi][jt][r] = v;
                mx[mi][r] = fmaxf(mx[mi][r], v);
            }
    }
#pragma unroll
    for (int o = 1; o <= 8; o <<= 1)
#pragma unroll
        for (int mi = 0; mi < 2; mi++)
#pragma unroll
            for (int r = 0; r < 4; r++)
                mx[mi][r] = fmaxf(mx[mi][r], __shfl_xor(mx[mi][r], o));
#pragma unroll
    for (int jt = 0; jt < 12; jt++)
#pragma unroll
        for (int mi = 0; mi < 2; mi++)
#pragma unroll
            for (int r = 0; r < 4; r++) {
                float p = __expf(sc[mi][jt][r] - mx[mi][r]);
                sc[mi][jt][r] = p;
                sm[mi][r] += p;
            }
#pragma unroll
    for (int o = 1; o <= 8; o <<= 1)
#pragma unroll
        for (int mi = 0; mi < 2; mi++)
#pragma unroll
            for (int r = 0; r < 4; r++)
                sm[mi][r] += __shfl_xor(sm[mi][r], o);
#pragma unroll
    for (int mi = 0; mi < 2; mi++)
#pragma unroll
        for (int r = 0; r < 4; r++) inv[mi][r] = 1.0f / sm[mi][r];

    f32x4 oacc[2][4];
#pragma unroll
    for (int mi = 0; mi < 2; mi++)
#pragma unroll
        for (int dt = 0; dt < 4; dt++) oacc[mi][dt] = (f32x4){0.f, 0.f, 0.f, 0.f};
    __syncthreads();

#pragma unroll
    for (int ph = 0; ph < 2; ph++) {
#pragma unroll
        for (int jj = 0; jj < 6; jj++) {
            int jt = ph * 6 + jj;
#pragma unroll
            for (int mi = 0; mi < 2; mi++) {
                int row = w * 32 + mi * 16 + ls * 4;
#pragma unroll
                for (int r = 0; r < 4; r++)
                    Ps[(row + r) * 104 + jj * 16 + lr] = f2b(sc[mi][jt][r]);
            }
        }
        __syncthreads();
#pragma unroll
        for (int kk = 0; kk < 3; kk++) {
            U16x8 pf[2], vf[4];
#pragma unroll
            for (int mi = 0; mi < 2; mi++)
                pf[mi].u = *reinterpret_cast<const uint4*>(
                    Ps + (w * 32 + mi * 16 + lr) * 104 + kk * 32 + ls * 8);
#pragma unroll
            for (int dt = 0; dt < 4; dt++) {
                int rrow = dt * 16 + lr;
                int lch = ph * 12 + kk * 4 + ls;
                int pch = lch ^ (rrow & 7) ^ ((rrow >> 3) & 7);
                vf[dt].u = *reinterpret_cast<const uint4*>(Vs + ((rrow * 384 + pch * 16) >> 1));
            }
#pragma unroll
            for (int mi = 0; mi < 2; mi++)
#pragma unroll
                for (int dt = 0; dt < 4; dt++)
                    oacc[mi][dt] = __builtin_amdgcn_mfma_f32_16x16x32_bf16(
                        pf[mi].s, vf[dt].s, oacc[mi][dt], 0, 0, 0);
        }
        __syncthreads();
    }

#pragma unroll
    for (int mi = 0; mi < 2; mi++)
#pragma unroll
        for (int dt = 0; dt < 4; dt++)
#pragma unroll
            for (int r = 0; r < 4; r++) {
                float v = oacc[mi][dt][r] * inv[mi][r];
                Ctx[(size_t)(qrow0 + mi * 16 + ls * 4 + r) * 768 + h * 64 + dt * 16 + lr] = f2b(v);
            }
}

extern "C" void kernel_launch(void* const* d_in, const int* in_sizes, int n_in,
                              void* d_out, int out_size, void* d_ws, size_t ws_size,
                              hipStream_t stream) {
    (void)in_sizes; (void)n_in; (void)out_size; (void)ws_size;
    const float* x    = (const float*)d_in[0];
    const float* Wq   = (const float*)d_in[1];
    const float* bq   = (const float*)d_in[2];
    const float* Wk   = (const float*)d_in[3];
    const float* bk   = (const float*)d_in[4];
    const float* Wv   = (const float*)d_in[5];
    const float* bv   = (const float*)d_in[6];
    const float* Wo   = (const float*)d_in[7];
    const float* bo   = (const float*)d_in[8];
    const float* ln1g = (const float*)d_in[9];
    const float* ln1b = (const float*)d_in[10];
    const float* W1   = (const float*)d_in[11];
    const float* b1   = (const float*)d_in[12];
    const float* W2   = (const float*)d_in[13];
    const float* b2   = (const float*)d_in[14];
    const float* ln2g = (const float*)d_in[15];
    const float* ln2b = (const float*)d_in[16];
    float* out = (float*)d_out;

    char* ws = (char*)d_ws;
    size_t off = 0;
    auto alloc = [&](size_t bytes) -> char* {
        char* p = ws + off;
        off += (bytes + 255) & ~(size_t)255;
        return p;
    };
    u16* WqkvT = (u16*)alloc(2 * 3 * D2 * sizeof(u16));  // per layer: [Q;K;V] rows
    u16* WoT   = (u16*)alloc(2 * D2 * sizeof(u16));
    u16* W1T   = (u16*)alloc(2 * DI * sizeof(u16));
    u16* W2T   = (u16*)alloc(2 * DI * sizeof(u16));
    u16* Xb    = (u16*)alloc(AD * sizeof(u16));
    u16* RegA  = (u16*)alloc(4 * AD * sizeof(u16)); // Qb,Kb,Vb,Ctxb; reused as H1b
    u16*   AttnB = (u16*)alloc(AD * sizeof(u16));
    u16*   H2b   = (u16*)alloc(AD * sizeof(u16));
    u16* Qb = RegA;
    u16* Kb = RegA + AD;
    u16* Vb = RegA + 2 * AD;    // row-major like Q/K
    u16* Ctxb = RegA + 3 * AD;
    u16* H1b = RegA;

    // fused prep: x cast (12288 blocks) + 12 weight transposes (13824 blocks)
    prep_all<<<dim3(26112), 256, 0, stream>>>(
        x, Xb, Wq, Wk, Wv, Wo, W1, W2, WqkvT, WoT, W1T, W2T);

    const size_t LDSB = 32768;
    const float* xres = x;
    for (int l = 0; l < 2; l++) {
        // fused QKV: N=2304 (bands Q|K|V), all outputs row-major bf16
        gemm128<5><<<dim3(128 * 18), 256, LDSB, stream>>>(
            Xb, WqkvT + (size_t)l * 3 * D2, bq + l * 768, bk + l * 768, bv + l * 768,
            Qb, Kb, Vb, ROWS, 2304, 768, 18);
        attn_mfma<<<dim3(BB * NBLK * HH), 256, 0, stream>>>(Qb, Kb, Vb, Ctxb);
        gemm128<0><<<dim3(128 * 6), 256, LDSB, stream>>>(
            Ctxb, WoT + l * D2, bo + l * 768, nullptr, nullptr,
            H2b, nullptr, nullptr, ROWS, 768, 768, 6);
        // LN1: bf16 GEMM out + f32 residual -> bf16 attn_out (no f32 copy)
        resid_ln2<true, false><<<dim3(ROWS / 4), 256, 0, stream>>>(
            H2b, (const void*)xres, ln1g + l * 768, ln1b + l * 768, nullptr, AttnB);
        gemm128<2><<<dim3(128 * 24), 256, LDSB, stream>>>(
            AttnB, W1T + l * DI, b1 + l * 3072, nullptr, nullptr,
            H1b, nullptr, nullptr, ROWS, 3072, 768, 24);
        gemm128<0><<<dim3(128 * 6), 256, LDSB, stream>>>(
            H1b, W2T + l * DI, b2 + l * 768, nullptr, nullptr,
            H2b, nullptr, nullptr, ROWS, 768, 3072, 6);
        float* outl = out + (size_t)l * AD;
        // LN2: bf16 GEMM out + bf16 attn_out residual -> f32 layer out + bf16 next-X
        resid_ln2<false, true><<<dim3(ROWS / 4), 256, 0, stream>>>(
            H2b, (const void*)AttnB, ln2g + l * 768, ln2b + l * 768, outl, Xb);
        xres = outl;
    }
}

// Round 19
// 801.040 us; speedup vs baseline: 1.5008x; 1.0051x over previous
//
#include <hip/hip_runtime.h>
#include <hip/hip_bf16.h>

typedef unsigned short u16;
typedef unsigned int u32;

static const int DD = 768;
static const int SS = 2048;
static const int BB = 8;
static const int HH = 12;
static const int NBLK = 16;   // S / 128
static const int ROWS = BB * SS;          // 16384
static const size_t AD = (size_t)ROWS * DD;   // activation element count
static const size_t D2 = (size_t)DD * DD;
static const size_t DI = (size_t)DD * 3072;

typedef __attribute__((ext_vector_type(8))) short short8;
typedef __attribute__((ext_vector_type(4))) float f32x4;

union U16x8 { uint4 u; short8 s; };

__device__ __forceinline__ float bl(u32 u) { return __uint_as_float(u << 16); }
__device__ __forceinline__ float bh(u32 u) { return __uint_as_float(u & 0xffff0000u); }
__device__ __forceinline__ u16 f2b(float f) {
    u32 u = __float_as_uint(f);
    u += 0x7fffu + ((u >> 16) & 1u);
    return (u16)(u >> 16);
}
__device__ __forceinline__ u32 pack2(float lo, float hi) {
    return (u32)f2b(lo) | ((u32)f2b(hi) << 16);
}

// async global->LDS, 16B per lane (dest is wave-uniform base + lane*16)
__device__ __forceinline__ void gload16(const u16* g, u16* l) {
    __builtin_amdgcn_global_load_lds(
        (const __attribute__((address_space(1))) void*)g,
        (__attribute__((address_space(3))) void*)l, 16, 0, 0);
}

// fast GELU (tanh form): v * sigmoid(2z), z = 0.7978845608(v + 0.044715 v^3)
__device__ __forceinline__ float gelu_fast(float v) {
    float z2 = 1.5957691216f * (v + 0.044715f * v * v * v);
    z2 = fminf(z2, 80.f);
    float e = __expf(z2);
    return v * (e / (e + 1.0f));
}

// ------------- fused prep: x cast + 12 weight transposes + bias concat -------
// One dispatch. Flat grid 26118 blocks:
//   [0, 12288): x f32 -> bf16, 1024 elems/block
//   [12288, 26112): 32x32 cast+transpose tiles (per layer 6912 tiles)
//   [26112, 26118): QKV bias concat: block b -> layer b/3, which b%3
__global__ __launch_bounds__(256) void prep_all(
    const float* __restrict__ x, u16* __restrict__ xb,
    const float* __restrict__ Wq, const float* __restrict__ Wk,
    const float* __restrict__ Wv, const float* __restrict__ Wo,
    const float* __restrict__ W1, const float* __restrict__ W2,
    u16* __restrict__ WqkvT, u16* __restrict__ WoT,
    u16* __restrict__ W1T, u16* __restrict__ W2T,
    const float* __restrict__ bq, const float* __restrict__ bk,
    const float* __restrict__ bv, float* __restrict__ bqkv) {
    const int bid = blockIdx.x;
    if (bid < 12288) {
        int i = (bid * 256 + threadIdx.x) * 4;
        float4 v = *reinterpret_cast<const float4*>(x + i);
        uint2 p;
        p.x = pack2(v.x, v.y);
        p.y = pack2(v.z, v.w);
        *reinterpret_cast<uint2*>(xb + i) = p;
        return;
    }
    if (bid >= 26112) {
        int b = bid - 26112;
        int layer = b / 3, which = b % 3;
        const float* src = (which == 0) ? bq : (which == 1) ? bk : bv;
        src += layer * 768;
        float* dst = bqkv + layer * 2304 + which * 768;
#pragma unroll
        for (int i = 0; i < 3; i++)
            dst[threadIdx.x + i * 256] = src[threadIdx.x + i * 256];
        return;
    }
    __shared__ float tile[32][33];
    int t = bid - 12288;
    const int layer = t / 6912;
    int r = t % 6912;
    const float* W;
    u16* WT;
    int K, N, bx, by;
    if (r < 2304) {
        int m = r / 576, tl = r % 576;
        K = 768; N = 768;
        bx = tl % 24; by = tl / 24;
        if (m == 0)      { W = Wq + (size_t)layer * D2; WT = WqkvT + (size_t)layer * 3 * D2; }
        else if (m == 1) { W = Wk + (size_t)layer * D2; WT = WqkvT + (size_t)layer * 3 * D2 + D2; }
        else if (m == 2) { W = Wv + (size_t)layer * D2; WT = WqkvT + (size_t)layer * 3 * D2 + 2 * D2; }
        else             { W = Wo + (size_t)layer * D2; WT = WoT + (size_t)layer * D2; }
    } else if (r < 4608) {
        int tl = r - 2304;
        K = 768; N = 3072;
        bx = tl % 96; by = tl / 96;
        W = W1 + (size_t)layer * DI;
        WT = W1T + (size_t)layer * DI;
    } else {
        int tl = r - 4608;
        K = 3072; N = 768;
        bx = tl % 24; by = tl / 24;
        W = W2 + (size_t)layer * DI;
        WT = W2T + (size_t)layer * DI;
    }
    const int tx = threadIdx.x & 31, ty = threadIdx.x >> 5;
#pragma unroll
    for (int i = 0; i < 4; i++) {
        int kr = by * 32 + ty + i * 8;
        tile[ty + i * 8][tx] = W[(size_t)kr * N + bx * 32 + tx];
    }
    __syncthreads();
#pragma unroll
    for (int i = 0; i < 4; i++) {
        int nr = bx * 32 + ty + i * 8;
        WT[(size_t)nr * K + by * 32 + tx] = f2b(tile[tx][ty + i * 8]);
    }
}

// ---------------- 128x128 MFMA GEMM, BK=32 dbuf, 4 blocks/CU, unroll x2 ------
// r14/r17 configuration (session best). Chunked XCD swizzle is a WIN (+5%
// total, r16 A/B): consecutive tn-blocks share the A M-panel, swizzle keeps
// them on one XCD -> panel L2-hot.
// EPI 0: bf16 out; 2: gelu->bf16 out. QKV now uses EPI 0 with N=2304 and a
// concatenated bias (r19: single contiguous output stream; attention reads
// Q/K/V at stride 2304).
// LDS swizzle (rule #21, both sides): 16B-slot phys = logical ^ ((row>>1)&3).
// Requires NT = K/32 even (call sites: 24, 96).
template <int EPI>
__global__ __launch_bounds__(256, 4) void gemm128(const u16* __restrict__ A,
                                                  const u16* __restrict__ BT,
                                                  const float* __restrict__ b0,
                                                  void* __restrict__ C0,
                                                  int M, int N, int K, int NTN) {
    extern __shared__ u16 smem[];  // 2 slots x 8192 u16 (16KB) = 32KB
    const int tid = threadIdx.x;
    const int nwg = gridDim.x;
    int wg = blockIdx.x;
    // chunked bijective XCD swizzle (all grids divisible by 8)
    wg = (wg & 7) * (nwg >> 3) + (wg >> 3);
    const int tn = wg % NTN, tm = wg / NTN;   // row-major: A M-panel stays hot
    const int m0 = tm * 128, n0 = tn * 128;
    const int lane = tid & 63, w = tid >> 6;
    const int wr = w >> 1, wc = w & 1;
    const int lr = lane & 15, ls = lane >> 4;
    const int sl = ls ^ ((lr >> 1) & 3);      // 2-way-optimal swizzled slot

    const int r3 = tid >> 2, c2 = tid & 3;
    const int kswz = ((c2 ^ ((r3 >> 1) & 3)) << 3);  // pre-swizzled src k-offset
    const u16* sA = A + (size_t)(m0 + r3) * K + kswz;   // incremental sources
    const u16* sB = BT + (size_t)(n0 + r3) * K + kswz;
    const size_t rstep = (size_t)64 * K;       // 64 rows per chunk

    f32x4 acc[4][4];
#pragma unroll
    for (int i = 0; i < 4; i++)
#pragma unroll
        for (int j = 0; j < 4; j++) acc[i][j] = (f32x4){0.f, 0.f, 0.f, 0.f};

#define STAGE_SLOT(SLOT)                                                      \
    {                                                                         \
        u16* pA = smem + (SLOT) * 8192 + tid * 8;                             \
        u16* pB = smem + (SLOT) * 8192 + 4096 + tid * 8;                      \
        gload16(sA, pA);                                                      \
        gload16(sA + rstep, pA + 2048);                                       \
        gload16(sB, pB);                                                      \
        gload16(sB + rstep, pB + 2048);                                       \
        sA += 32;                                                             \
        sB += 32;                                                             \
    }
#define COMPUTE_SLOT(SLOT)                                                    \
    {                                                                         \
        const u16* bufA = smem + (SLOT) * 8192 + (wr * 64 + lr) * 32;         \
        const u16* bufB = smem + (SLOT) * 8192 + 4096 + (wc * 64 + lr) * 32;  \
        U16x8 af[4], bf[4];                                                   \
        _Pragma("unroll") for (int ni = 0; ni < 4; ni++)                      \
            bf[ni].u = *(const uint4*)(bufB + ni * 512 + sl * 8);             \
        _Pragma("unroll") for (int mi = 0; mi < 4; mi++)                      \
            af[mi].u = *(const uint4*)(bufA + mi * 512 + sl * 8);             \
        _Pragma("unroll") for (int mi = 0; mi < 4; mi++)                      \
            _Pragma("unroll") for (int ni = 0; ni < 4; ni++)                  \
                acc[mi][ni] = __builtin_amdgcn_mfma_f32_16x16x32_bf16(        \
                    af[mi].s, bf[ni].s, acc[mi][ni], 0, 0, 0);                \
    }

    const int NT = K >> 5;   // even at all call sites
    STAGE_SLOT(0)            // prologue: tile 0 -> slot 0
    __syncthreads();

    for (int t = 0; t < NT; t += 2) {
        if (t + 1 < NT) STAGE_SLOT(1)   // prefetch tile t+1
        COMPUTE_SLOT(0)                 // compute tile t
        __syncthreads();
        if (t + 2 < NT) STAGE_SLOT(0)   // prefetch tile t+2
        COMPUTE_SLOT(1)                 // compute tile t+1
        __syncthreads();
    }
#undef STAGE_SLOT
#undef COMPUTE_SLOT

    // epilogue
#pragma unroll
    for (int mi = 0; mi < 4; mi++) {
        int row0 = m0 + wr * 64 + mi * 16 + ls * 4;
#pragma unroll
        for (int ni = 0; ni < 4; ni++) {
            int col = n0 + wc * 64 + ni * 16 + lr;
            float bs = b0[col];
            float v[4];
#pragma unroll
            for (int r = 0; r < 4; r++) {
                v[r] = acc[mi][ni][r] + bs;
                if (EPI == 2) v[r] = gelu_fast(v[r]);
                ((u16*)C0)[(size_t)(row0 + r) * N + col] = f2b(v[r]);
            }
        }
    }
}

// ------- residual add + LayerNorm, wave-per-row (no LDS, no barriers) -------
// a: bf16 [rows][768]; res: f32 or bf16; writes bf16 ob and optionally f32 of.
// 4 rows per 256-thread block; lane handles 12 elems (3 x 4 at stride 256).
template <bool RESF32, bool OUTF32>
__global__ __launch_bounds__(256) void resid_ln2(const u16* __restrict__ a,
                                                 const void* __restrict__ res,
                                                 const float* __restrict__ g,
                                                 const float* __restrict__ be,
                                                 float* __restrict__ of,
                                                 u16* __restrict__ ob) {
    const int row = blockIdx.x * 4 + (threadIdx.x >> 6);
    const int lane = threadIdx.x & 63;
    const size_t base = (size_t)row * 768;
    float v[12];
    float s = 0.f;
#pragma unroll
    for (int i = 0; i < 3; i++) {
        int c = lane * 4 + i * 256;
        uint2 av = *reinterpret_cast<const uint2*>(a + base + c);
        float rv0, rv1, rv2, rv3;
        if (RESF32) {
            float4 r4 = *reinterpret_cast<const float4*>((const float*)res + base + c);
            rv0 = r4.x; rv1 = r4.y; rv2 = r4.z; rv3 = r4.w;
        } else {
            uint2 r2 = *reinterpret_cast<const uint2*>((const u16*)res + base + c);
            rv0 = bl(r2.x); rv1 = bh(r2.x); rv2 = bl(r2.y); rv3 = bh(r2.y);
        }
        v[i * 4 + 0] = bl(av.x) + rv0;
        v[i * 4 + 1] = bh(av.x) + rv1;
        v[i * 4 + 2] = bl(av.y) + rv2;
        v[i * 4 + 3] = bh(av.y) + rv3;
        s += v[i * 4 + 0] + v[i * 4 + 1] + v[i * 4 + 2] + v[i * 4 + 3];
    }
#pragma unroll
    for (int o = 1; o < 64; o <<= 1) s += __shfl_xor(s, o);
    float mean = s * (1.f / 768.f);
    float q = 0.f;
#pragma unroll
    for (int i = 0; i < 12; i++) {
        float d = v[i] - mean;
        q += d * d;
    }
#pragma unroll
    for (int o = 1; o < 64; o <<= 1) q += __shfl_xor(q, o);
    float inv = rsqrtf(q * (1.f / 768.f) + 1e-12f);
#pragma unroll
    for (int i = 0; i < 3; i++) {
        int c = lane * 4 + i * 256;
        float4 g4 = *reinterpret_cast<const float4*>(g + c);
        float4 b4 = *reinterpret_cast<const float4*>(be + c);
        float y0 = (v[i * 4 + 0] - mean) * inv * g4.x + b4.x;
        float y1 = (v[i * 4 + 1] - mean) * inv * g4.y + b4.y;
        float y2 = (v[i * 4 + 2] - mean) * inv * g4.z + b4.z;
        float y3 = (v[i * 4 + 3] - mean) * inv * g4.w + b4.w;
        if (OUTF32) {
            float4 o4 = {y0, y1, y2, y3};
            *reinterpret_cast<float4*>(of + base + c) = o4;
        }
        uint2 ob2;
        ob2.x = pack2(y0, y1);
        ob2.y = pack2(y2, y3);
        *reinterpret_cast<uint2*>(ob + base + c) = ob2;
    }
}

// ---------------- halo block attention (MFMA) ----------------
// QKV packed [B*S][2304] bf16 (Q|K|V bands). V transposed into LDS at stage.
__global__ __launch_bounds__(256) void attn_mfma(const u16* __restrict__ QKV,
                                                 u16* __restrict__ Ctx) {
    __shared__ u16 sm0[128 * 104];  // P (padded stride 104); also K [192][64] swizzled
    __shared__ u16 sm1[64 * 192];   // V^T [64 feat][192 tok] chunk-swizzled
    u16* Ks = sm0;
    u16* Ps = sm0;
    u16* Vs = sm1;

    const int bid = blockIdx.x;
    const int h = bid % HH;
    const int n = (bid / HH) % NBLK;
    const int b = bid / (HH * NBLK);
    const int tid = threadIdx.x;
    const int lane = tid & 63, w = tid >> 6;
    const int lr = lane & 15, ls = lane >> 4;
    const int s0 = n * 128 - 32;

#pragma unroll
    for (int j = 0; j < 6; j++) {
        int r = (tid >> 3) + j * 32;
        int c = tid & 7;
        int s = min(max(s0 + r, 0), SS - 1);
        uint4 kv = *reinterpret_cast<const uint4*>(
            QKV + ((size_t)(b * SS + s)) * 2304 + 768 + h * 64 + c * 8);
        int byteo = r * 128 + ((c * 16) ^ ((r & 7) << 4));
        *reinterpret_cast<uint4*>(Ks + (byteo >> 1)) = kv;
    }
#pragma unroll
    for (int j = 0; j < 6; j++) {
        int r = (tid >> 3) + j * 32;          // window token
        int c = tid & 7;                      // feature chunk (8 features)
        int s = min(max(s0 + r, 0), SS - 1);
        uint4 vv = *reinterpret_cast<const uint4*>(
            QKV + ((size_t)(b * SS + s)) * 2304 + 1536 + h * 64 + c * 8);
        const u16* e = reinterpret_cast<const u16*>(&vv);
        int chunk = r >> 3;
        int bo = (r & 7) * 2;
#pragma unroll
        for (int i = 0; i < 8; i++) {
            int d = c * 8 + i;
            int pch = chunk ^ (d & 7) ^ ((d >> 3) & 7);
            Vs[(d * 384 + pch * 16 + bo) >> 1] = e[i];
        }
    }
    __syncthreads();

    const int qrow0 = b * SS + n * 128 + w * 32;
    U16x8 qf[2][2];
#pragma unroll
    for (int mi = 0; mi < 2; mi++)
#pragma unroll
        for (int ks = 0; ks < 2; ks++)
            qf[mi][ks].u = *reinterpret_cast<const uint4*>(
                QKV + (size_t)(qrow0 + mi * 16 + lr) * 2304 + h * 64 + ks * 32 + ls * 8);

    f32x4 sc[2][12];
#pragma unroll
    for (int mi = 0; mi < 2; mi++)
#pragma unroll
        for (int jt = 0; jt < 12; jt++) sc[mi][jt] = (f32x4){0.f, 0.f, 0.f, 0.f};
#pragma unroll
    for (int jt = 0; jt < 12; jt++) {
        U16x8 kf[2];
#pragma unroll
        for (int ks = 0; ks < 2; ks++) {
            int r = jt * 16 + lr;
            int byteo = r * 128 + ((ks * 64 + ls * 16) ^ ((r & 7) << 4));
            kf[ks].u = *reinterpret_cast<const uint4*>(Ks + (byteo >> 1));
        }
#pragma unroll
        for (int mi = 0; mi < 2; mi++)
#pragma unroll
            for (int ks = 0; ks < 2; ks++)
                sc[mi][jt] = __builtin_amdgcn_mfma_f32_16x16x32_bf16(
                    qf[mi][ks].s, kf[ks].s, sc[mi][jt], 0, 0, 0);
    }

    const int lo = (n == 0) ? 32 : 0;
    const int hi = (n == NBLK - 1) ? 160 : 192;
    float mx[2][4], sm[2][4], inv[2][4];
#pragma unroll
    for (int mi = 0; mi < 2; mi++)
#pragma unroll
        for (int r = 0; r < 4; r++) { mx[mi][r] = -3.0e38f; sm[mi][r] = 0.f; }
#pragma unroll
    for (int jt = 0; jt < 12; jt++) {
        int col = jt * 16 + lr;
        bool valid = (col >= lo) && (col < hi);
#pragma unroll
        for (int mi = 0; mi < 2; mi++)
#pragma unroll
            for (int r = 0; r < 4; r++) {
                float v = valid ? sc[mi][jt][r] * 0.125f : -3.0e38f;
                sc[mi][jt][r] = v;
                mx[mi][r] = fmaxf(mx[mi][r], v);
            }
    }
#pragma unroll
    for (int o = 1; o <= 8; o <<= 1)
#pragma unroll
        for (int mi = 0; mi < 2; mi++)
#pragma unroll
            for (int r = 0; r < 4; r++)
                mx[mi][r] = fmaxf(mx[mi][r], __shfl_xor(mx[mi][r], o));
#pragma unroll
    for (int jt = 0; jt < 12; jt++)
#pragma unroll
        for (int mi = 0; mi < 2; mi++)
#pragma unroll
            for (int r = 0; r < 4; r++) {
                float p = __expf(sc[mi][jt][r] - mx[mi][r]);
                sc[mi][jt][r] = p;
                sm[mi][r] += p;
            }
#pragma unroll
    for (int o = 1; o <= 8; o <<= 1)
#pragma unroll
        for (int mi = 0; mi < 2; mi++)
#pragma unroll
            for (int r = 0; r < 4; r++)
                sm[mi][r] += __shfl_xor(sm[mi][r], o);
#pragma unroll
    for (int mi = 0; mi < 2; mi++)
#pragma unroll
        for (int r = 0; r < 4; r++) inv[mi][r] = 1.0f / sm[mi][r];

    f32x4 oacc[2][4];
#pragma unroll
    for (int mi = 0; mi < 2; mi++)
#pragma unroll
        for (int dt = 0; dt < 4; dt++) oacc[mi][dt] = (f32x4){0.f, 0.f, 0.f, 0.f};
    __syncthreads();

#pragma unroll
    for (int ph = 0; ph < 2; ph++) {
#pragma unroll
        for (int jj = 0; jj < 6; jj++) {
            int jt = ph * 6 + jj;
#pragma unroll
            for (int mi = 0; mi < 2; mi++) {
                int row = w * 32 + mi * 16 + ls * 4;
#pragma unroll
                for (int r = 0; r < 4; r++)
                    Ps[(row + r) * 104 + jj * 16 + lr] = f2b(sc[mi][jt][r]);
            }
        }
        __syncthreads();
#pragma unroll
        for (int kk = 0; kk < 3; kk++) {
            U16x8 pf[2], vf[4];
#pragma unroll
            for (int mi = 0; mi < 2; mi++)
                pf[mi].u = *reinterpret_cast<const uint4*>(
                    Ps + (w * 32 + mi * 16 + lr) * 104 + kk * 32 + ls * 8);
#pragma unroll
            for (int dt = 0; dt < 4; dt++) {
                int rrow = dt * 16 + lr;
                int lch = ph * 12 + kk * 4 + ls;
                int pch = lch ^ (rrow & 7) ^ ((rrow >> 3) & 7);
                vf[dt].u = *reinterpret_cast<const uint4*>(Vs + ((rrow * 384 + pch * 16) >> 1));
            }
#pragma unroll
            for (int mi = 0; mi < 2; mi++)
#pragma unroll
                for (int dt = 0; dt < 4; dt++)
                    oacc[mi][dt] = __builtin_amdgcn_mfma_f32_16x16x32_bf16(
                        pf[mi].s, vf[dt].s, oacc[mi][dt], 0, 0, 0);
        }
        __syncthreads();
    }

#pragma unroll
    for (int mi = 0; mi < 2; mi++)
#pragma unroll
        for (int dt = 0; dt < 4; dt++)
#pragma unroll
            for (int r = 0; r < 4; r++) {
                float v = oacc[mi][dt][r] * inv[mi][r];
                Ctx[(size_t)(qrow0 + mi * 16 + ls * 4 + r) * 768 + h * 64 + dt * 16 + lr] = f2b(v);
            }
}

extern "C" void kernel_launch(void* const* d_in, const int* in_sizes, int n_in,
                              void* d_out, int out_size, void* d_ws, size_t ws_size,
                              hipStream_t stream) {
    (void)in_sizes; (void)n_in; (void)out_size; (void)ws_size;
    const float* x    = (const float*)d_in[0];
    const float* Wq   = (const float*)d_in[1];
    const float* bq   = (const float*)d_in[2];
    const float* Wk   = (const float*)d_in[3];
    const float* bk   = (const float*)d_in[4];
    const float* Wv   = (const float*)d_in[5];
    const float* bv   = (const float*)d_in[6];
    const float* Wo   = (const float*)d_in[7];
    const float* bo   = (const float*)d_in[8];
    const float* ln1g = (const float*)d_in[9];
    const float* ln1b = (const float*)d_in[10];
    const float* W1   = (const float*)d_in[11];
    const float* b1   = (const float*)d_in[12];
    const float* W2   = (const float*)d_in[13];
    const float* b2   = (const float*)d_in[14];
    const float* ln2g = (const float*)d_in[15];
    const float* ln2b = (const float*)d_in[16];
    float* out = (float*)d_out;

    char* ws = (char*)d_ws;
    size_t off = 0;
    auto alloc = [&](size_t bytes) -> char* {
        char* p = ws + off;
        off += (bytes + 255) & ~(size_t)255;
        return p;
    };
    u16* WqkvT = (u16*)alloc(2 * 3 * D2 * sizeof(u16));  // per layer: [Q;K;V] rows
    u16* WoT   = (u16*)alloc(2 * D2 * sizeof(u16));
    u16* W1T   = (u16*)alloc(2 * DI * sizeof(u16));
    u16* W2T   = (u16*)alloc(2 * DI * sizeof(u16));
    float* bqkv = (float*)alloc(2 * 2304 * sizeof(float));
    u16* Xb    = (u16*)alloc(AD * sizeof(u16));
    u16* RegA  = (u16*)alloc(4 * AD * sizeof(u16)); // QKVb(3AD)+Ctxb; reused as H1b
    u16*   AttnB = (u16*)alloc(AD * sizeof(u16));
    u16*   H2b   = (u16*)alloc(AD * sizeof(u16));
    u16* QKVb = RegA;           // packed [row][2304]
    u16* Ctxb = RegA + 3 * AD;
    u16* H1b  = RegA;           // overwrites QKVb/Ctxb after O-proj (both dead)

    // fused prep: x cast + 12 weight transposes + QKV bias concat
    prep_all<<<dim3(26118), 256, 0, stream>>>(
        x, Xb, Wq, Wk, Wv, Wo, W1, W2, WqkvT, WoT, W1T, W2T, bq, bk, bv, bqkv);

    const size_t LDSB = 32768;
    const float* xres = x;
    for (int l = 0; l < 2; l++) {
        // fused QKV: single contiguous output [row][2304], concat bias
        gemm128<0><<<dim3(128 * 18), 256, LDSB, stream>>>(
            Xb, WqkvT + (size_t)l * 3 * D2, bqkv + l * 2304,
            QKVb, ROWS, 2304, 768, 18);
        attn_mfma<<<dim3(BB * NBLK * HH), 256, 0, stream>>>(QKVb, Ctxb);
        gemm128<0><<<dim3(128 * 6), 256, LDSB, stream>>>(
            Ctxb, WoT + l * D2, bo + l * 768, H2b, ROWS, 768, 768, 6);
        // LN1: bf16 GEMM out + f32 residual -> bf16 attn_out
        resid_ln2<true, false><<<dim3(ROWS / 4), 256, 0, stream>>>(
            H2b, (const void*)xres, ln1g + l * 768, ln1b + l * 768, nullptr, AttnB);
        gemm128<2><<<dim3(128 * 24), 256, LDSB, stream>>>(
            AttnB, W1T + l * DI, b1 + l * 3072, H1b, ROWS, 3072, 768, 24);
        gemm128<0><<<dim3(128 * 6), 256, LDSB, stream>>>(
            H1b, W2T + l * DI, b2 + l * 768, H2b, ROWS, 768, 3072, 6);
        float* outl = out + (size_t)l * AD;
        // LN2: bf16 GEMM out + bf16 attn_out residual -> f32 layer out + bf16 next-X
        resid_ln2<false, true><<<dim3(ROWS / 4), 256, 0, stream>>>(
            H2b, (const void*)AttnB, ln2g + l * 768, ln2b + l * 768, outl, Xb);
        xres = outl;
    }
}